// Round 7
// baseline (198.454 us; speedup 1.0000x reference)
//
#include <hip/hip_runtime.h>
#include <math.h>

#define NB 16
#define NT 512
#define NSZ 512
#define NH 8
#define NHD 64
#define MAXR 16

#define C_D0 6.3f
#define C_STD 1.4f
#define C_GAMMA 2.0f

#define NEGINF (-1e30f)
#define LOG2E 1.4426950408889634f
#define C1F   0.18033688011112042f   // 0.125 * log2(e)

typedef unsigned short u16;
typedef __attribute__((ext_vector_type(8))) short bf16x8;
typedef __attribute__((ext_vector_type(4))) float f32x4;
typedef __attribute__((ext_vector_type(8))) unsigned short u16x8;

__device__ __forceinline__ u16 f2b(float f) {
    union { float f; unsigned int u; } c; c.f = f;
    unsigned int u = c.u + 0x7FFFu + ((c.u >> 16) & 1u);
    return (u16)(u >> 16);
}
__device__ __forceinline__ float b2f(u16 h) {
    union { unsigned int u; float f; } c; c.u = ((unsigned int)h) << 16;
    return c.f;
}

#if __has_builtin(__builtin_amdgcn_exp2f)
__device__ __forceinline__ float exp2_fast(float x) { return __builtin_amdgcn_exp2f(x); }
#else
__device__ __forceinline__ float exp2_fast(float x) { return exp2f(x); }
#endif

#define GL2LDS(gp, lp) __builtin_amdgcn_global_load_lds( \
    (const __attribute__((address_space(1))) void*)(gp), \
    (__attribute__((address_space(3))) void*)(lp), 16, 0, 0)

// swizzled u16-index of 16B chunk c in row r (row = 8 chunks = 64 bf16)
#define SWU(r, c) ((((r) * 8) + ((c) ^ ((r) & 7))) * 8)

// ---------------------------------------------------------------------------
// fp32 -> bf16 converts
// ---------------------------------------------------------------------------
__global__ __launch_bounds__(256) void cvt3_bf16(
    const float* __restrict__ s0, const float* __restrict__ s1,
    const float* __restrict__ s2, u16* __restrict__ d0,
    u16* __restrict__ d1, u16* __restrict__ d2, int n)
{
    const float* s = blockIdx.y == 0 ? s0 : (blockIdx.y == 1 ? s1 : s2);
    u16* d = blockIdx.y == 0 ? d0 : (blockIdx.y == 1 ? d1 : d2);
    int i = (blockIdx.x * 256 + threadIdx.x) * 8;
    if (i >= n) return;
    float4 a = *(const float4*)&s[i];
    float4 b = *(const float4*)&s[i + 4];
    u16x8 v;
    v[0]=f2b(a.x); v[1]=f2b(a.y); v[2]=f2b(a.z); v[3]=f2b(a.w);
    v[4]=f2b(b.x); v[5]=f2b(b.y); v[6]=f2b(b.z); v[7]=f2b(b.w);
    *(u16x8*)&d[i] = v;
}

__global__ __launch_bounds__(256) void cvt4_bf16(
    const float* __restrict__ s0, const float* __restrict__ s1,
    const float* __restrict__ s2, const float* __restrict__ s3,
    u16* __restrict__ d0, u16* __restrict__ d1,
    u16* __restrict__ d2, u16* __restrict__ d3, int n)
{
    const float* s; u16* d;
    switch (blockIdx.y) {
        case 0: s = s0; d = d0; break;
        case 1: s = s1; d = d1; break;
        case 2: s = s2; d = d2; break;
        default: s = s3; d = d3; break;
    }
    int i = (blockIdx.x * 256 + threadIdx.x) * 8;
    if (i >= n) return;
    float4 a = *(const float4*)&s[i];
    float4 b = *(const float4*)&s[i + 4];
    u16x8 v;
    v[0]=f2b(a.x); v[1]=f2b(a.y); v[2]=f2b(a.z); v[3]=f2b(a.w);
    v[4]=f2b(b.x); v[5]=f2b(b.y); v[6]=f2b(b.z); v[7]=f2b(b.w);
    *(u16x8*)&d[i] = v;
}

__global__ void bcat_k(const float* __restrict__ bq, const float* __restrict__ bk,
                       const float* __restrict__ bv, float* __restrict__ bc)
{
    int i = blockIdx.x * 256 + threadIdx.x;
    if (i >= 1536) return;
    bc[i] = i < 512 ? bq[i] : (i < 1024 ? bk[i - 512] : bv[i - 1024]);
}

// ---------------------------------------------------------------------------
// QKV projections, z-batched (m97 structure, proven in R3)
// ---------------------------------------------------------------------------
__global__ __launch_bounds__(256) void gemm_qkv(
    const u16* __restrict__ A0, const u16* __restrict__ A1, const u16* __restrict__ A2,
    const u16* __restrict__ Wc, const float* __restrict__ bc,
    u16* __restrict__ pkv)
{
    __shared__ u16 Al[128 * 32];
    __shared__ u16 Bl[128 * 32];
    const int z = blockIdx.z;
    const u16* A = z == 0 ? A0 : (z == 1 ? A1 : A2);
    const u16* W = Wc + (size_t)z * NSZ * NSZ;
    const float* bias = bc + z * NSZ;
    const int tid = threadIdx.x;
    const int m0 = blockIdx.x * 128;
    const int n0 = blockIdx.y * 128;
    const int w = tid >> 6, lane = tid & 63;
    const int wm = (w >> 1) * 64, wn = (w & 1) * 64;
    const int fr = lane & 15, fk = lane >> 4;

    f32x4 acc[4][4] = {};
    for (int k0 = 0; k0 < NSZ; k0 += 32) {
        #pragma unroll
        for (int p = 0; p < 2; ++p) {
            int s = tid + p * 256;
            int row = s >> 2, cb = s & 3;
            GL2LDS(&A[(size_t)(m0 + row) * NSZ + k0 + cb * 8], &Al[s * 8]);
            GL2LDS(&W[(size_t)(n0 + row) * NSZ + k0 + cb * 8], &Bl[s * 8]);
        }
        __syncthreads();
        bf16x8 af[4], bfr[4];
        #pragma unroll
        for (int mf = 0; mf < 4; ++mf)
            af[mf] = *(const bf16x8*)&Al[(wm + mf * 16 + fr) * 32 + fk * 8];
        #pragma unroll
        for (int nf = 0; nf < 4; ++nf)
            bfr[nf] = *(const bf16x8*)&Bl[(wn + nf * 16 + fr) * 32 + fk * 8];
        #pragma unroll
        for (int mf = 0; mf < 4; ++mf)
            #pragma unroll
            for (int nf = 0; nf < 4; ++nf)
                acc[mf][nf] = __builtin_amdgcn_mfma_f32_16x16x32_bf16(
                    af[mf], bfr[nf], acc[mf][nf], 0, 0, 0);
        __syncthreads();
    }
    #pragma unroll
    for (int mf = 0; mf < 4; ++mf) {
        #pragma unroll
        for (int nf = 0; nf < 4; ++nf) {
            int col = n0 + wn + nf * 16 + fr;
            float bv = bias[col];
            #pragma unroll
            for (int r = 0; r < 4; ++r) {
                int rowg = m0 + wm + mf * 16 + fk * 4 + r;
                pkv[(size_t)rowg * 1536 + z * 512 + col] = f2b(acc[mf][nf][r] + bv);
            }
        }
    }
}

// ---------------------------------------------------------------------------
// Output projection (fp32 out)
// ---------------------------------------------------------------------------
__global__ __launch_bounds__(256) void gemm_out(
    const u16* __restrict__ A, const u16* __restrict__ W,
    const float* __restrict__ bias, float* __restrict__ Cout, int M, int N, int K)
{
    __shared__ u16 Al[128 * 32];
    __shared__ u16 Bl[128 * 32];
    const int tid = threadIdx.x;
    const int m0 = blockIdx.x * 128;
    const int n0 = blockIdx.y * 128;
    const int w = tid >> 6, lane = tid & 63;
    const int wm = (w >> 1) * 64, wn = (w & 1) * 64;
    const int fr = lane & 15, fk = lane >> 4;

    f32x4 acc[4][4] = {};
    for (int k0 = 0; k0 < K; k0 += 32) {
        #pragma unroll
        for (int p = 0; p < 2; ++p) {
            int s = tid + p * 256;
            int row = s >> 2, cb = s & 3;
            GL2LDS(&A[(size_t)(m0 + row) * K + k0 + cb * 8], &Al[s * 8]);
            GL2LDS(&W[(size_t)(n0 + row) * K + k0 + cb * 8], &Bl[s * 8]);
        }
        __syncthreads();
        bf16x8 af[4], bfr[4];
        #pragma unroll
        for (int mf = 0; mf < 4; ++mf)
            af[mf] = *(const bf16x8*)&Al[(wm + mf * 16 + fr) * 32 + fk * 8];
        #pragma unroll
        for (int nf = 0; nf < 4; ++nf)
            bfr[nf] = *(const bf16x8*)&Bl[(wn + nf * 16 + fr) * 32 + fk * 8];
        #pragma unroll
        for (int mf = 0; mf < 4; ++mf)
            #pragma unroll
            for (int nf = 0; nf < 4; ++nf)
                acc[mf][nf] = __builtin_amdgcn_mfma_f32_16x16x32_bf16(
                    af[mf], bfr[nf], acc[mf][nf], 0, 0, 0);
        __syncthreads();
    }
    #pragma unroll
    for (int mf = 0; mf < 4; ++mf) {
        #pragma unroll
        for (int nf = 0; nf < 4; ++nf) {
            int col = n0 + wn + nf * 16 + fr;
            float bv = bias[col];
            #pragma unroll
            for (int r = 0; r < 4; ++r) {
                int rowg = m0 + wm + mf * 16 + fk * 4 + r;
                Cout[(size_t)rowg * N + col] = acc[mf][nf][r] + bv;
            }
        }
    }
}

// ---------------------------------------------------------------------------
// Fused 3x depthwise conv1d(k=5) + 3 scalar gates + mD.
// Wave-per-token: 256 thr = 4 waves, wave w owns token blockIdx.x*4+w.
// 8 channels per lane; all reductions via __shfl_xor (no barriers).
// ---------------------------------------------------------------------------
__global__ __launch_bounds__(256) void conv_gate_all(
    const u16* __restrict__ xn, u16* __restrict__ pkv,
    const float* __restrict__ Wcq, const float* __restrict__ Wck, const float* __restrict__ Wcv,
    const float* __restrict__ Wgq, const float* __restrict__ bgq,
    const float* __restrict__ Wgk, const float* __restrict__ bgk,
    const float* __restrict__ Wgv, const float* __restrict__ bgv,
    const float* __restrict__ WmD, const float* __restrict__ bmD,
    float* __restrict__ mD)
{
    const int w = threadIdx.x >> 6, lane = threadIdx.x & 63;
    const int bt = blockIdx.x * 4 + w;
    const int b = bt >> 9, tpos = bt & (NT - 1);
    const int c0 = lane * 8;

    float x[5][8];
    #pragma unroll
    for (int j = 0; j < 5; ++j) {
        int tt = tpos + j - 2;
        if (tt >= 0 && tt < NT) {
            u16x8 v = *(const u16x8*)&xn[((size_t)(b*NT + tt))*NSZ + c0];
            #pragma unroll
            for (int i = 0; i < 8; ++i) x[j][i] = b2f(v[i]);
        } else {
            #pragma unroll
            for (int i = 0; i < 8; ++i) x[j][i] = 0.f;
        }
    }
    const size_t rb = (size_t)bt * 1536;
    u16x8 q8 = *(const u16x8*)&pkv[rb + c0];
    u16x8 k8 = *(const u16x8*)&pkv[rb + 512 + c0];
    u16x8 v8 = *(const u16x8*)&pkv[rb + 1024 + c0];

    float aq[8], ak[8], av[8];
    float sq = 0.f, sk = 0.f, sv = 0.f;
    #pragma unroll
    for (int i = 0; i < 8; ++i) {
        int c = c0 + i;
        float a0 = 0.f, a1 = 0.f, a2 = 0.f;
        #pragma unroll
        for (int j = 0; j < 5; ++j) {
            a0 += x[j][i] * Wcq[c*5 + j];
            a1 += x[j][i] * Wck[c*5 + j];
            a2 += x[j][i] * Wcv[c*5 + j];
        }
        aq[i] = a0; ak[i] = a1; av[i] = a2;
        sq += b2f(q8[i]) * Wgq[c] + a0 * Wgq[512 + c];
        sk += b2f(k8[i]) * Wgk[c] + a1 * Wgk[512 + c];
        sv += b2f(v8[i]) * Wgv[c] + a2 * Wgv[512 + c];
    }
    #pragma unroll
    for (int o = 1; o < 64; o <<= 1) {
        sq += __shfl_xor(sq, o, 64);
        sk += __shfl_xor(sk, o, 64);
        sv += __shfl_xor(sv, o, 64);
    }
    float gq = 1.f / (1.f + expf(-(sq + bgq[0])));
    float gk = 1.f / (1.f + expf(-(sk + bgk[0])));
    float gv = 1.f / (1.f + expf(-(sv + bgv[0])));

    u16x8 oq8, ok8, ov8;
    float smd = 0.f;
    #pragma unroll
    for (int i = 0; i < 8; ++i) {
        float oq = (1.f - gq) * b2f(q8[i]) + gq * aq[i];
        oq8[i] = f2b(oq);
        ok8[i] = f2b((1.f - gk) * b2f(k8[i]) + gk * ak[i]);
        ov8[i] = f2b((1.f - gv) * b2f(v8[i]) + gv * av[i]);
        smd += oq * WmD[c0 + i];
    }
    *(u16x8*)&pkv[rb + c0]        = oq8;
    *(u16x8*)&pkv[rb + 512 + c0]  = ok8;
    *(u16x8*)&pkv[rb + 1024 + c0] = ov8;
    #pragma unroll
    for (int o = 1; o < 64; o <<= 1) smd += __shfl_xor(smd, o, 64);
    if (lane == 0)
        mD[bt] = C_D0 + 2.f * C_STD * tanhf((smd + bmD[0]) / C_GAMMA);
}

// ---------------------------------------------------------------------------
// V transpose: pkv v-section (b,t,h*64+d) -> vpT[(b*8+h)*64+d][t]
// ---------------------------------------------------------------------------
__global__ __launch_bounds__(256) void vtrans(
    const u16* __restrict__ pkv, u16* __restrict__ vpT)
{
    __shared__ u16 lt[64][72];
    const int t0 = blockIdx.x * 64;
    const int h = blockIdx.y, b = blockIdx.z;
    const int tid = threadIdx.x;
    #pragma unroll
    for (int p = 0; p < 2; ++p) {
        int s = tid + p * 256;
        int t = s >> 3, c8 = s & 7;
        u16x8 v = *(const u16x8*)&pkv[((size_t)(b*NT + t0 + t))*1536 + 1024 + h*NHD + c8*8];
        *(u16x8*)&lt[t][c8 * 8] = v;
    }
    __syncthreads();
    #pragma unroll
    for (int p = 0; p < 2; ++p) {
        int s = tid + p * 256;
        int d = s >> 3, c8 = s & 7;
        u16x8 o;
        #pragma unroll
        for (int j = 0; j < 8; ++j) o[j] = lt[c8 * 8 + j][d];
        *(u16x8*)&vpT[((size_t)((b*NH + h)*NHD + d))*NT + t0 + c8*8] = o;
    }
}

// ---------------------------------------------------------------------------
// MFMA flash attention — LDS-diet version (37.3 KB -> 4 blocks/CU).
// Single K/V LDS buffer + register prefetch of next tile; 2 barriers/tile.
//   - Pl aliases Ql (Q register-resident after prologue)
//   - rpk aliases Vl during prologue (V0 ds_write deferred until after qdr)
//   - qdr table + epilogue rpe_v staged as bf16
//   - rvl aliases Kl in the epilogue
// ---------------------------------------------------------------------------
__global__ __launch_bounds__(256) void attn_mfma(
    const u16* __restrict__ pkv, const u16* __restrict__ vpT,
    const float* __restrict__ mD, const int* __restrict__ mask,
    const float* __restrict__ rpe, u16* __restrict__ cxh)
{
    __shared__ __align__(16) char smem[38144];
    u16*  QP    = (u16*)(smem);              // Q (prologue) then P / out-bounce
    u16*  Kl    = (u16*)(smem + 8192);       // K tile; epilogue: rvl bf16 [33][64]
    u16*  Vl    = (u16*)(smem + 16384);      // V tile; prologue: rpk [48][64] swz
    u16*  rpk   = (u16*)(smem + 16384);
    u16*  rvl16 = (u16*)(smem + 8192);
    u16*  qdrl  = (u16*)(smem + 24576);      // [64][36] bf16
    float* wbufl= (float*)(smem + 29184);    // [64][34] fp32
    float* inv2s= (float*)(smem + 37888);    // [64]

    const int tid  = threadIdx.x;
    const int lane = tid & 63;
    const int w    = tid >> 6;
    const int wq0  = w * 16;
    const int fr   = lane & 15;
    const int fq   = lane >> 4;
    const int b    = blockIdx.x >> 3;
    const int h    = blockIdx.x & 7;
    const int q0   = blockIdx.y * 64;

    const size_t qbase  = ((size_t)(b*NT + q0)) * 1536 + h * NHD;
    const size_t kbaseg = ((size_t)b * NT) * 1536 + 512 + h * NHD;
    const size_t vbaseg = ((size_t)((b*NH + h) * NHD)) * NT;

    // ---- prologue: reg-load Q, K0, V0; swizzled ds_write of Q, K0 ----
    int r_[2], cs_[2];
    u16x8 qreg[2], kreg[2], vreg[2];
    #pragma unroll
    for (int p = 0; p < 2; ++p) {
        int s = tid + p * 256;
        r_[p] = s >> 3; cs_[p] = s & 7;
        qreg[p] = *(const u16x8*)(pkv + qbase  + (size_t)r_[p] * 1536 + cs_[p] * 8);
        kreg[p] = *(const u16x8*)(pkv + kbaseg + (size_t)r_[p] * 1536 + cs_[p] * 8);
        vreg[p] = *(const u16x8*)(vpT + vbaseg + (size_t)r_[p] * NT   + cs_[p] * 8);
    }
    #pragma unroll
    for (int p = 0; p < 2; ++p) {
        *(u16x8*)(QP + SWU(r_[p], cs_[p])) = qreg[p];
        *(u16x8*)(Kl + SWU(r_[p], cs_[p])) = kreg[p];
    }
    // rpe_k -> rpk (in Vl space): 264 chunks, strided (264 > 256 threads!)
    for (int idx = tid; idx < 264; idx += 256) {
        int r = idx >> 3, c = idx & 7;
        float4 f0 = *(const float4*)&rpe[r * 128 + c * 8];
        float4 f1 = *(const float4*)&rpe[r * 128 + c * 8 + 4];
        u16x8 vv;
        vv[0]=f2b(f0.x); vv[1]=f2b(f0.y); vv[2]=f2b(f0.z); vv[3]=f2b(f0.w);
        vv[4]=f2b(f1.x); vv[5]=f2b(f1.y); vv[6]=f2b(f1.z); vv[7]=f2b(f1.w);
        *(u16x8*)(rpk + SWU(r, c)) = vv;
    }
    if (tid < 120) {   // zero rows 33..47
        u16x8 vv = {0,0,0,0,0,0,0,0};
        *(u16x8*)(rpk + (((33 + (tid >> 3)) * 8) + (tid & 7)) * 8) = vv;
    }
    if (tid < 64) {
        float md = mD[b * NT + q0 + tid];
        inv2s[tid] = 2.f * LOG2E / (md * md);
    }
    for (int i = tid; i < 64 * 34; i += 256) wbufl[i] = 0.f;
    int nt;
    {
        unsigned long long bal = __ballot(lane < 8 && mask[b * NT + lane * 64] != 0);
        nt = bal ? (int)__ffsll(bal) - 1 : 8;
    }
    __syncthreads();                                // (P0)

    // persistent Q A-frags (Ql dead afterwards -> QP becomes Pl)
    bf16x8 aq0 = *(const bf16x8*)(QP + SWU(wq0 + fr, fq));
    bf16x8 aq1 = *(const bf16x8*)(QP + SWU(wq0 + fr, 4 + fq));

    // qdr[q][rd] = q . rpe_k[rd] via MFMA (reads rpk in Vl space)
    {
        f32x4 qd[3] = {};
        #pragma unroll
        for (int nf = 0; nf < 3; ++nf) {
            bf16x8 b0 = *(const bf16x8*)(rpk + SWU(nf * 16 + fr, fq));
            bf16x8 b1 = *(const bf16x8*)(rpk + SWU(nf * 16 + fr, 4 + fq));
            qd[nf] = __builtin_amdgcn_mfma_f32_16x16x32_bf16(aq0, b0, qd[nf], 0, 0, 0);
            qd[nf] = __builtin_amdgcn_mfma_f32_16x16x32_bf16(aq1, b1, qd[nf], 0, 0, 0);
        }
        #pragma unroll
        for (int nf = 0; nf < 3; ++nf) {
            int rd = nf * 16 + fr;
            if (rd < 33) {
                #pragma unroll
                for (int r = 0; r < 4; ++r)
                    qdrl[(wq0 + fq * 4 + r) * 36 + rd] = f2b(qd[nf][r]);
            }
        }
    }
    __syncthreads();                                // (P1) qdr done; rpk dead
    // V0 ds_write into Vl (visible at iter0's barrier (1))
    #pragma unroll
    for (int p = 0; p < 2; ++p)
        *(u16x8*)(Vl + SWU(r_[p], cs_[p])) = vreg[p];

    f32x4 O[4] = {};
    float m2[4] = {NEGINF, NEGINF, NEGINF, NEGINF};
    float li[4] = {};

    for (int t = 0; t < nt; ++t) {
        const int kb = t * 64;
        const bool pre = (t + 1 < nt);
        u16x8 kreg2[2], vreg2[2];
        if (pre) {
            const int kn = kb + 64;
            #pragma unroll
            for (int p = 0; p < 2; ++p) {
                kreg2[p] = *(const u16x8*)(pkv + kbaseg + (size_t)(kn + r_[p]) * 1536 + cs_[p] * 8);
                vreg2[p] = *(const u16x8*)(vpT + vbaseg + (size_t)r_[p] * NT + kn + cs_[p] * 8);
            }
        }
        int mk[4];
        #pragma unroll
        for (int nf = 0; nf < 4; ++nf) mk[nf] = mask[b * NT + kb + nf * 16 + fr];

        // ---- QK^T ----
        f32x4 s_[4] = {};
        #pragma unroll
        for (int nf = 0; nf < 4; ++nf) {
            bf16x8 b0 = *(const bf16x8*)(Kl + SWU(nf * 16 + fr, fq));
            bf16x8 b1 = *(const bf16x8*)(Kl + SWU(nf * 16 + fr, 4 + fq));
            s_[nf] = __builtin_amdgcn_mfma_f32_16x16x32_bf16(aq0, b0, s_[nf], 0, 0, 0);
            s_[nf] = __builtin_amdgcn_mfma_f32_16x16x32_bf16(aq1, b1, s_[nf], 0, 0, 0);
        }
        // ---- softmax (log2 domain) ----
        const bool leftfar  = (kb + 79 <= q0);
        const bool rightfar = (kb >= q0 + 79);
        const bool mid = !leftfar && !rightfar;

        float p_[4][4], alpha[4], rsum_[4], ls_[4], rs_[4];
        #pragma unroll
        for (int r = 0; r < 4; ++r) {
            const int lq = wq0 + fq * 4 + r;
            const int qg = q0 + lq;
            const float iv = inv2s[lq];
            const float qf = leftfar ? b2f(qdrl[lq * 36]) : (rightfar ? b2f(qdrl[lq * 36 + 32]) : 0.f);
            float mx = NEGINF;
            #pragma unroll
            for (int nf = 0; nf < 4; ++nf) {
                const int kg = kb + nf * 16 + fr;
                float sc;
                if (mk[nf]) sc = NEGINF;
                else {
                    float qr = mid ? b2f(qdrl[lq * 36 + (min(max(kg - qg, -MAXR), MAXR) + MAXR)]) : qf;
                    float fd = (float)(qg - kg);
                    sc = (s_[nf][r] + qr) * C1F - fd * fd * iv;
                }
                p_[r][nf] = sc;
                mx = fmaxf(mx, sc);
            }
            mx = fmaxf(mx, __shfl_xor(mx, 1, 64));
            mx = fmaxf(mx, __shfl_xor(mx, 2, 64));
            mx = fmaxf(mx, __shfl_xor(mx, 4, 64));
            mx = fmaxf(mx, __shfl_xor(mx, 8, 64));
            float mn = fmaxf(m2[r], mx);
            alpha[r] = exp2_fast(m2[r] - mn);
            m2[r] = mn;
            float rsum = 0.f, ls = 0.f, rs = 0.f;
            #pragma unroll
            for (int nf = 0; nf < 4; ++nf) {
                float pv = exp2_fast(p_[r][nf] - mn);
                p_[r][nf] = pv;
                rsum += pv;
                if (mid) {
                    int kg = kb + nf * 16 + fr;
                    if (kg <= qg - MAXR) ls += pv;
                    else if (kg >= qg + MAXR) rs += pv;
                }
            }
            rsum += __shfl_xor(rsum, 1, 64); rsum += __shfl_xor(rsum, 2, 64);
            rsum += __shfl_xor(rsum, 4, 64); rsum += __shfl_xor(rsum, 8, 64);
            if (mid) {
                ls += __shfl_xor(ls, 1, 64); ls += __shfl_xor(ls, 2, 64);
                ls += __shfl_xor(ls, 4, 64); ls += __shfl_xor(ls, 8, 64);
                rs += __shfl_xor(rs, 1, 64); rs += __shfl_xor(rs, 2, 64);
                rs += __shfl_xor(rs, 4, 64); rs += __shfl_xor(rs, 8, 64);
            }
            li[r] = li[r] * alpha[r] + rsum;
            rsum_[r] = rsum; ls_[r] = ls; rs_[r] = rs;
        }
        // O rescale
        #pragma unroll
        for (int nf = 0; nf < 4; ++nf) {
            O[nf][0] *= alpha[0]; O[nf][1] *= alpha[1];
            O[nf][2] *= alpha[2]; O[nf][3] *= alpha[3];
        }
        // wbuf rescale + tile contributions
        #pragma unroll
        for (int r = 0; r < 4; ++r) {
            int lq = wq0 + fq * 4 + r;
            if (alpha[r] != 1.f) {
                for (int c = fr; c < 33; c += 16) wbufl[lq * 34 + c] *= alpha[r];
            }
        }
        if (fr == 0) {
            #pragma unroll
            for (int r = 0; r < 4; ++r) {
                int lq = wq0 + fq * 4 + r;
                if (leftfar)       wbufl[lq * 34]      += rsum_[r];
                else if (rightfar) wbufl[lq * 34 + 32] += rsum_[r];
                else { wbufl[lq * 34] += ls_[r]; wbufl[lq * 34 + 32] += rs_[r]; }
            }
        }
        if (mid) {
            #pragma unroll
            for (int r = 0; r < 4; ++r) {
                int lq = wq0 + fq * 4 + r, qg = q0 + lq;
                #pragma unroll
                for (int nf = 0; nf < 4; ++nf) {
                    int d = kb + nf * 16 + fr - qg;
                    if (d > -MAXR && d < MAXR) wbufl[lq * 34 + d + MAXR] += p_[r][nf];
                }
            }
        }
        // ---- P -> bf16 LDS (swizzled, in QP space) ----
        #pragma unroll
        for (int r = 0; r < 4; ++r) {
            int lq = wq0 + fq * 4 + r;
            #pragma unroll
            for (int nf = 0; nf < 4; ++nf) {
                int k = nf * 16 + fr;
                QP[lq * 64 + (((k >> 3) ^ (lq & 7)) << 3) + (k & 7)] = f2b(p_[r][nf]);
            }
        }
        __syncthreads();    // (1) P + V(t) visible; all QK reads of Kl done
        // K(t+1) into Kl (QK done; PV doesn't touch Kl)
        if (pre) {
            #pragma unroll
            for (int p = 0; p < 2; ++p)
                *(u16x8*)(Kl + SWU(r_[p], cs_[p])) = kreg2[p];
        }
        // ---- PV ----
        bf16x8 ap0 = *(const bf16x8*)(QP + SWU(wq0 + fr, fq));
        bf16x8 ap1 = *(const bf16x8*)(QP + SWU(wq0 + fr, 4 + fq));
        #pragma unroll
        for (int nf = 0; nf < 4; ++nf) {
            bf16x8 v0 = *(const bf16x8*)(Vl + SWU(nf * 16 + fr, fq));
            bf16x8 v1 = *(const bf16x8*)(Vl + SWU(nf * 16 + fr, 4 + fq));
            O[nf] = __builtin_amdgcn_mfma_f32_16x16x32_bf16(ap0, v0, O[nf], 0, 0, 0);
            O[nf] = __builtin_amdgcn_mfma_f32_16x16x32_bf16(ap1, v1, O[nf], 0, 0, 0);
        }
        __syncthreads();    // (2) PV reads of Vl/QP done; K(t+1) visible
        // V(t+1) into Vl (visible at next iter's barrier (1))
        if (pre) {
            #pragma unroll
            for (int p = 0; p < 2; ++p)
                *(u16x8*)(Vl + SWU(r_[p], cs_[p])) = vreg2[p];
        }
    }

    // ---- epilogue: rpe_v (bf16, in Kl space) via wbuf buckets ----
    for (int idx = tid; idx < 264; idx += 256) {   // strided: 264 > 256
        int r = idx >> 3, c = idx & 7;
        float4 f0 = *(const float4*)&rpe[r * 128 + 64 + c * 8];
        float4 f1 = *(const float4*)&rpe[r * 128 + 64 + c * 8 + 4];
        u16x8 vv;
        vv[0]=f2b(f0.x); vv[1]=f2b(f0.y); vv[2]=f2b(f0.z); vv[3]=f2b(f0.w);
        vv[4]=f2b(f1.x); vv[5]=f2b(f1.y); vv[6]=f2b(f1.z); vv[7]=f2b(f1.w);
        *(u16x8*)(rvl16 + (r * 8 + c) * 8) = vv;
    }
    __syncthreads();
    for (int rd = 0; rd < 33; ++rd) {
        float rvv[4];
        #pragma unroll
        for (int nf = 0; nf < 4; ++nf) rvv[nf] = b2f(rvl16[rd * 64 + nf * 16 + fr]);
        #pragma unroll
        for (int r = 0; r < 4; ++r) {
            float wv = wbufl[(wq0 + fq * 4 + r) * 34 + rd];
            #pragma unroll
            for (int nf = 0; nf < 4; ++nf) O[nf][r] += wv * rvv[nf];
        }
    }
    float invl[4];
    #pragma unroll
    for (int r = 0; r < 4; ++r) invl[r] = 1.f / li[r];
    #pragma unroll
    for (int r = 0; r < 4; ++r) {
        int lq = wq0 + fq * 4 + r;
        #pragma unroll
        for (int nf = 0; nf < 4; ++nf)
            QP[lq * 64 + nf * 16 + fr] = f2b(O[nf][r] * invl[r]);   // linear bounce
    }
    __syncthreads();
    #pragma unroll
    for (int j = 0; j < 2; ++j) {
        int s = w * 128 + j * 64 + lane;
        int rr = s >> 3, c8 = s & 7;
        u16x8 vv = *(const u16x8*)(QP + rr * 64 + c8 * 8);
        *(u16x8*)&cxh[((size_t)(b*NT + q0 + rr)) * 512 + h * NHD + c8 * 8] = vv;
    }
}

// ---------------------------------------------------------------------------
extern "C" void kernel_launch(void* const* d_in, const int* in_sizes, int n_in,
                              void* d_out, int out_size, void* d_ws, size_t ws_size,
                              hipStream_t stream) {
    const float* key   = (const float*)d_in[0];
    const float* value = (const float*)d_in[1];
    const float* query = (const float*)d_in[2];
    const int*   mask  = (const int*)d_in[3];
    const float* Wq  = (const float*)d_in[4];
    const float* bq  = (const float*)d_in[5];
    const float* Wk  = (const float*)d_in[6];
    const float* bk  = (const float*)d_in[7];
    const float* Wv  = (const float*)d_in[8];
    const float* bv  = (const float*)d_in[9];
    const float* Wcq = (const float*)d_in[10];
    const float* Wck = (const float*)d_in[11];
    const float* Wcv = (const float*)d_in[12];
    const float* Wgq = (const float*)d_in[13];
    const float* bgq = (const float*)d_in[14];
    const float* Wgk = (const float*)d_in[15];
    const float* bgk = (const float*)d_in[16];
    const float* Wgv = (const float*)d_in[17];
    const float* bgv = (const float*)d_in[18];
    const float* WmD = (const float*)d_in[19];
    const float* bmD = (const float*)d_in[20];
    const float* rpe = (const float*)d_in[21];
    const float* Wo  = (const float*)d_in[22];
    const float* bo  = (const float*)d_in[23];
    float* out = (float*)d_out;

    const size_t NTOK = (size_t)NB * NT;            // 8192
    const size_t NE   = NTOK * NSZ;                 // 4,194,304
    const size_t NW   = (size_t)NSZ * NSZ;          // 262,144

    u16* ws16 = (u16*)d_ws;
    u16* qx   = ws16;                // bf16 inputs
    u16* kx   = qx + NE;
    u16* vx   = kx + NE;
    u16* pkv  = vx + NE;             // (8192, 1536) q|k|v
    u16* wcat = pkv + NTOK * 1536;   // 3 x (512,512)
    u16* woh  = wcat + 3 * NW;
    u16* vpT  = woh + NW;            // (16*8*64, 512)
    u16* cxh  = vpT + NE;            // (8192, 512)
    float* bcat = (float*)(cxh + NE);
    float* mDb  = bcat + 1536;

    cvt3_bf16<<<dim3((unsigned)(NE/8/256), 3), 256, 0, stream>>>(
        query, key, value, qx, kx, vx, (int)NE);
    cvt4_bf16<<<dim3((unsigned)(NW/8/256), 4), 256, 0, stream>>>(
        Wq, Wk, Wv, Wo, wcat, wcat + NW, wcat + 2*NW, woh, (int)NW);
    bcat_k<<<6, 256, 0, stream>>>(bq, bk, bv, bcat);

    gemm_qkv<<<dim3(64, 4, 3), 256, 0, stream>>>(qx, kx, vx, wcat, bcat, pkv);

    conv_gate_all<<<(int)(NTOK / 4), 256, 0, stream>>>(
        kx, pkv, Wcq, Wck, Wcv, Wgq, bgq, Wgk, bgk, Wgv, bgv, WmD, bmD, mDb);

    vtrans<<<dim3(8, 8, 16), 256, 0, stream>>>(pkv, vpT);

    attn_mfma<<<dim3(128, 8), 256, 0, stream>>>(pkv, vpT, mDb, mask, rpe, cxh);

    gemm_out<<<dim3(64, 4), 256, 0, stream>>>(cxh, woh, bo, out, (int)NTOK, NSZ, NSZ);
}

// Round 8
// 160.904 us; speedup vs baseline: 1.2334x; 1.2334x over previous
//
#include <hip/hip_runtime.h>
#include <math.h>

#define NB 16
#define NT 512
#define NSZ 512
#define NH 8
#define NHD 64
#define MAXR 16

#define C_D0 6.3f
#define C_STD 1.4f
#define C_GAMMA 2.0f

#define NEGINF (-1e30f)
#define LOG2E 1.4426950408889634f
#define C1F   0.18033688011112042f   // 0.125 * log2(e)

typedef unsigned short u16;
typedef __attribute__((ext_vector_type(8))) short bf16x8;
typedef __attribute__((ext_vector_type(4))) float f32x4;
typedef __attribute__((ext_vector_type(8))) unsigned short u16x8;

__device__ __forceinline__ u16 f2b(float f) {
    union { float f; unsigned int u; } c; c.f = f;
    unsigned int u = c.u + 0x7FFFu + ((c.u >> 16) & 1u);
    return (u16)(u >> 16);
}
__device__ __forceinline__ float b2f(u16 h) {
    union { unsigned int u; float f; } c; c.u = ((unsigned int)h) << 16;
    return c.f;
}

#if __has_builtin(__builtin_amdgcn_exp2f)
__device__ __forceinline__ float exp2_fast(float x) { return __builtin_amdgcn_exp2f(x); }
#else
__device__ __forceinline__ float exp2_fast(float x) { return exp2f(x); }
#endif

#define GL2LDS(gp, lp) __builtin_amdgcn_global_load_lds( \
    (const __attribute__((address_space(1))) void*)(gp), \
    (__attribute__((address_space(3))) void*)(lp), 16, 0, 0)

// swizzled u16-index of 16B chunk c in row r (row = 8 chunks = 64 bf16)
#define SWU(r, c) ((((r) * 8) + ((c) ^ ((r) & 7))) * 8)

// ---------------------------------------------------------------------------
// fp32 -> bf16 converts
// ---------------------------------------------------------------------------
__global__ __launch_bounds__(256) void cvt3_bf16(
    const float* __restrict__ s0, const float* __restrict__ s1,
    const float* __restrict__ s2, u16* __restrict__ d0,
    u16* __restrict__ d1, u16* __restrict__ d2, int n)
{
    const float* s = blockIdx.y == 0 ? s0 : (blockIdx.y == 1 ? s1 : s2);
    u16* d = blockIdx.y == 0 ? d0 : (blockIdx.y == 1 ? d1 : d2);
    int i = (blockIdx.x * 256 + threadIdx.x) * 8;
    if (i >= n) return;
    float4 a = *(const float4*)&s[i];
    float4 b = *(const float4*)&s[i + 4];
    u16x8 v;
    v[0]=f2b(a.x); v[1]=f2b(a.y); v[2]=f2b(a.z); v[3]=f2b(a.w);
    v[4]=f2b(b.x); v[5]=f2b(b.y); v[6]=f2b(b.z); v[7]=f2b(b.w);
    *(u16x8*)&d[i] = v;
}

__global__ __launch_bounds__(256) void cvt4_bf16(
    const float* __restrict__ s0, const float* __restrict__ s1,
    const float* __restrict__ s2, const float* __restrict__ s3,
    u16* __restrict__ d0, u16* __restrict__ d1,
    u16* __restrict__ d2, u16* __restrict__ d3, int n)
{
    const float* s; u16* d;
    switch (blockIdx.y) {
        case 0: s = s0; d = d0; break;
        case 1: s = s1; d = d1; break;
        case 2: s = s2; d = d2; break;
        default: s = s3; d = d3; break;
    }
    int i = (blockIdx.x * 256 + threadIdx.x) * 8;
    if (i >= n) return;
    float4 a = *(const float4*)&s[i];
    float4 b = *(const float4*)&s[i + 4];
    u16x8 v;
    v[0]=f2b(a.x); v[1]=f2b(a.y); v[2]=f2b(a.z); v[3]=f2b(a.w);
    v[4]=f2b(b.x); v[5]=f2b(b.y); v[6]=f2b(b.z); v[7]=f2b(b.w);
    *(u16x8*)&d[i] = v;
}

__global__ void bcat_k(const float* __restrict__ bq, const float* __restrict__ bk,
                       const float* __restrict__ bv, float* __restrict__ bc)
{
    int i = blockIdx.x * 256 + threadIdx.x;
    if (i >= 1536) return;
    bc[i] = i < 512 ? bq[i] : (i < 1024 ? bk[i - 512] : bv[i - 1024]);
}

// ---------------------------------------------------------------------------
// QKV projections, z-batched (m97 structure, proven in R3)
// ---------------------------------------------------------------------------
__global__ __launch_bounds__(256) void gemm_qkv(
    const u16* __restrict__ A0, const u16* __restrict__ A1, const u16* __restrict__ A2,
    const u16* __restrict__ Wc, const float* __restrict__ bc,
    u16* __restrict__ pkv)
{
    __shared__ u16 Al[128 * 32];
    __shared__ u16 Bl[128 * 32];
    const int z = blockIdx.z;
    const u16* A = z == 0 ? A0 : (z == 1 ? A1 : A2);
    const u16* W = Wc + (size_t)z * NSZ * NSZ;
    const float* bias = bc + z * NSZ;
    const int tid = threadIdx.x;
    const int m0 = blockIdx.x * 128;
    const int n0 = blockIdx.y * 128;
    const int w = tid >> 6, lane = tid & 63;
    const int wm = (w >> 1) * 64, wn = (w & 1) * 64;
    const int fr = lane & 15, fk = lane >> 4;

    f32x4 acc[4][4] = {};
    for (int k0 = 0; k0 < NSZ; k0 += 32) {
        #pragma unroll
        for (int p = 0; p < 2; ++p) {
            int s = tid + p * 256;
            int row = s >> 2, cb = s & 3;
            GL2LDS(&A[(size_t)(m0 + row) * NSZ + k0 + cb * 8], &Al[s * 8]);
            GL2LDS(&W[(size_t)(n0 + row) * NSZ + k0 + cb * 8], &Bl[s * 8]);
        }
        __syncthreads();
        bf16x8 af[4], bfr[4];
        #pragma unroll
        for (int mf = 0; mf < 4; ++mf)
            af[mf] = *(const bf16x8*)&Al[(wm + mf * 16 + fr) * 32 + fk * 8];
        #pragma unroll
        for (int nf = 0; nf < 4; ++nf)
            bfr[nf] = *(const bf16x8*)&Bl[(wn + nf * 16 + fr) * 32 + fk * 8];
        #pragma unroll
        for (int mf = 0; mf < 4; ++mf)
            #pragma unroll
            for (int nf = 0; nf < 4; ++nf)
                acc[mf][nf] = __builtin_amdgcn_mfma_f32_16x16x32_bf16(
                    af[mf], bfr[nf], acc[mf][nf], 0, 0, 0);
        __syncthreads();
    }
    #pragma unroll
    for (int mf = 0; mf < 4; ++mf) {
        #pragma unroll
        for (int nf = 0; nf < 4; ++nf) {
            int col = n0 + wn + nf * 16 + fr;
            float bv = bias[col];
            #pragma unroll
            for (int r = 0; r < 4; ++r) {
                int rowg = m0 + wm + mf * 16 + fk * 4 + r;
                pkv[(size_t)rowg * 1536 + z * 512 + col] = f2b(acc[mf][nf][r] + bv);
            }
        }
    }
}

// ---------------------------------------------------------------------------
// Output projection (fp32 out)
// ---------------------------------------------------------------------------
__global__ __launch_bounds__(256) void gemm_out(
    const u16* __restrict__ A, const u16* __restrict__ W,
    const float* __restrict__ bias, float* __restrict__ Cout, int M, int N, int K)
{
    __shared__ u16 Al[128 * 32];
    __shared__ u16 Bl[128 * 32];
    const int tid = threadIdx.x;
    const int m0 = blockIdx.x * 128;
    const int n0 = blockIdx.y * 128;
    const int w = tid >> 6, lane = tid & 63;
    const int wm = (w >> 1) * 64, wn = (w & 1) * 64;
    const int fr = lane & 15, fk = lane >> 4;

    f32x4 acc[4][4] = {};
    for (int k0 = 0; k0 < K; k0 += 32) {
        #pragma unroll
        for (int p = 0; p < 2; ++p) {
            int s = tid + p * 256;
            int row = s >> 2, cb = s & 3;
            GL2LDS(&A[(size_t)(m0 + row) * K + k0 + cb * 8], &Al[s * 8]);
            GL2LDS(&W[(size_t)(n0 + row) * K + k0 + cb * 8], &Bl[s * 8]);
        }
        __syncthreads();
        bf16x8 af[4], bfr[4];
        #pragma unroll
        for (int mf = 0; mf < 4; ++mf)
            af[mf] = *(const bf16x8*)&Al[(wm + mf * 16 + fr) * 32 + fk * 8];
        #pragma unroll
        for (int nf = 0; nf < 4; ++nf)
            bfr[nf] = *(const bf16x8*)&Bl[(wn + nf * 16 + fr) * 32 + fk * 8];
        #pragma unroll
        for (int mf = 0; mf < 4; ++mf)
            #pragma unroll
            for (int nf = 0; nf < 4; ++nf)
                acc[mf][nf] = __builtin_amdgcn_mfma_f32_16x16x32_bf16(
                    af[mf], bfr[nf], acc[mf][nf], 0, 0, 0);
        __syncthreads();
    }
    #pragma unroll
    for (int mf = 0; mf < 4; ++mf) {
        #pragma unroll
        for (int nf = 0; nf < 4; ++nf) {
            int col = n0 + wn + nf * 16 + fr;
            float bv = bias[col];
            #pragma unroll
            for (int r = 0; r < 4; ++r) {
                int rowg = m0 + wm + mf * 16 + fk * 4 + r;
                Cout[(size_t)rowg * N + col] = acc[mf][nf][r] + bv;
            }
        }
    }
}

// ---------------------------------------------------------------------------
// Fused 3x depthwise conv1d(k=5) + 3 scalar gates + mD.
// Wave-per-token: 256 thr = 4 waves; 8 channels/lane; shfl reductions.
// ---------------------------------------------------------------------------
__global__ __launch_bounds__(256) void conv_gate_all(
    const u16* __restrict__ xn, u16* __restrict__ pkv,
    const float* __restrict__ Wcq, const float* __restrict__ Wck, const float* __restrict__ Wcv,
    const float* __restrict__ Wgq, const float* __restrict__ bgq,
    const float* __restrict__ Wgk, const float* __restrict__ bgk,
    const float* __restrict__ Wgv, const float* __restrict__ bgv,
    const float* __restrict__ WmD, const float* __restrict__ bmD,
    float* __restrict__ mD)
{
    const int w = threadIdx.x >> 6, lane = threadIdx.x & 63;
    const int bt = blockIdx.x * 4 + w;
    const int b = bt >> 9, tpos = bt & (NT - 1);
    const int c0 = lane * 8;

    float x[5][8];
    #pragma unroll
    for (int j = 0; j < 5; ++j) {
        int tt = tpos + j - 2;
        if (tt >= 0 && tt < NT) {
            u16x8 v = *(const u16x8*)&xn[((size_t)(b*NT + tt))*NSZ + c0];
            #pragma unroll
            for (int i = 0; i < 8; ++i) x[j][i] = b2f(v[i]);
        } else {
            #pragma unroll
            for (int i = 0; i < 8; ++i) x[j][i] = 0.f;
        }
    }
    const size_t rb = (size_t)bt * 1536;
    u16x8 q8 = *(const u16x8*)&pkv[rb + c0];
    u16x8 k8 = *(const u16x8*)&pkv[rb + 512 + c0];
    u16x8 v8 = *(const u16x8*)&pkv[rb + 1024 + c0];

    float aq[8], ak[8], av[8];
    float sq = 0.f, sk = 0.f, sv = 0.f;
    #pragma unroll
    for (int i = 0; i < 8; ++i) {
        int c = c0 + i;
        float a0 = 0.f, a1 = 0.f, a2 = 0.f;
        #pragma unroll
        for (int j = 0; j < 5; ++j) {
            a0 += x[j][i] * Wcq[c*5 + j];
            a1 += x[j][i] * Wck[c*5 + j];
            a2 += x[j][i] * Wcv[c*5 + j];
        }
        aq[i] = a0; ak[i] = a1; av[i] = a2;
        sq += b2f(q8[i]) * Wgq[c] + a0 * Wgq[512 + c];
        sk += b2f(k8[i]) * Wgk[c] + a1 * Wgk[512 + c];
        sv += b2f(v8[i]) * Wgv[c] + a2 * Wgv[512 + c];
    }
    #pragma unroll
    for (int o = 1; o < 64; o <<= 1) {
        sq += __shfl_xor(sq, o, 64);
        sk += __shfl_xor(sk, o, 64);
        sv += __shfl_xor(sv, o, 64);
    }
    float gq = 1.f / (1.f + expf(-(sq + bgq[0])));
    float gk = 1.f / (1.f + expf(-(sk + bgk[0])));
    float gv = 1.f / (1.f + expf(-(sv + bgv[0])));

    u16x8 oq8, ok8, ov8;
    float smd = 0.f;
    #pragma unroll
    for (int i = 0; i < 8; ++i) {
        float oq = (1.f - gq) * b2f(q8[i]) + gq * aq[i];
        oq8[i] = f2b(oq);
        ok8[i] = f2b((1.f - gk) * b2f(k8[i]) + gk * ak[i]);
        ov8[i] = f2b((1.f - gv) * b2f(v8[i]) + gv * av[i]);
        smd += oq * WmD[c0 + i];
    }
    *(u16x8*)&pkv[rb + c0]        = oq8;
    *(u16x8*)&pkv[rb + 512 + c0]  = ok8;
    *(u16x8*)&pkv[rb + 1024 + c0] = ov8;
    #pragma unroll
    for (int o = 1; o < 64; o <<= 1) smd += __shfl_xor(smd, o, 64);
    if (lane == 0)
        mD[bt] = C_D0 + 2.f * C_STD * tanhf((smd + bmD[0]) / C_GAMMA);
}

// ---------------------------------------------------------------------------
// V transpose: pkv v-section (b,t,h*64+d) -> vpT[(b*8+h)*64+d][t]
// ---------------------------------------------------------------------------
__global__ __launch_bounds__(256) void vtrans(
    const u16* __restrict__ pkv, u16* __restrict__ vpT)
{
    __shared__ u16 lt[64][72];
    const int t0 = blockIdx.x * 64;
    const int h = blockIdx.y, b = blockIdx.z;
    const int tid = threadIdx.x;
    #pragma unroll
    for (int p = 0; p < 2; ++p) {
        int s = tid + p * 256;
        int t = s >> 3, c8 = s & 7;
        u16x8 v = *(const u16x8*)&pkv[((size_t)(b*NT + t0 + t))*1536 + 1024 + h*NHD + c8*8];
        *(u16x8*)&lt[t][c8 * 8] = v;
    }
    __syncthreads();
    #pragma unroll
    for (int p = 0; p < 2; ++p) {
        int s = tid + p * 256;
        int d = s >> 3, c8 = s & 7;
        u16x8 o;
        #pragma unroll
        for (int j = 0; j < 8; ++j) o[j] = lt[c8 * 8 + j][d];
        *(u16x8*)&vpT[((size_t)((b*NH + h)*NHD + d))*NT + t0 + c8*8] = o;
    }
}

// ---------------------------------------------------------------------------
// MFMA flash attention — windowed version.
// The Gaussian decay -d^2/(m_D^2/2) with m_D<=9.1 suppresses keys at |d|>=65
// by >=102 nats (e-44 in fp32) relative to the best unmasked key, so only
// k-tiles {ct-1, ct, ct+1} (ct = min(q-tile, nt-1)) can contribute. The clamp
// handles q >= length: those rows concentrate on the last unmasked key.
// Everything else identical to the R7 (verified) kernel.
// ---------------------------------------------------------------------------
__global__ __launch_bounds__(256) void attn_mfma(
    const u16* __restrict__ pkv, const u16* __restrict__ vpT,
    const float* __restrict__ mD, const int* __restrict__ mask,
    const float* __restrict__ rpe, u16* __restrict__ cxh)
{
    __shared__ __align__(16) char smem[38144];
    u16*  QP    = (u16*)(smem);              // Q (prologue) then P / out-bounce
    u16*  Kl    = (u16*)(smem + 8192);       // K tile; epilogue: rvl bf16
    u16*  Vl    = (u16*)(smem + 16384);      // V tile; prologue: rpk [48][64] swz
    u16*  rpk   = (u16*)(smem + 16384);
    u16*  rvl16 = (u16*)(smem + 8192);
    u16*  qdrl  = (u16*)(smem + 24576);      // [64][36] bf16
    float* wbufl= (float*)(smem + 29184);    // [64][34] fp32
    float* inv2s= (float*)(smem + 37888);    // [64]

    const int tid  = threadIdx.x;
    const int lane = tid & 63;
    const int w    = tid >> 6;
    const int wq0  = w * 16;
    const int fr   = lane & 15;
    const int fq   = lane >> 4;
    const int b    = blockIdx.x >> 3;
    const int h    = blockIdx.x & 7;
    const int q0   = blockIdx.y * 64;

    const size_t qbase  = ((size_t)(b*NT + q0)) * 1536 + h * NHD;
    const size_t kbaseg = ((size_t)b * NT) * 1536 + 512 + h * NHD;
    const size_t vbaseg = ((size_t)((b*NH + h) * NHD)) * NT;

    // ---- tile window: nt from mask ballot, then clamp to diagonal +-1 ----
    int nt;
    {
        unsigned long long bal = __ballot(lane < 8 && mask[b * NT + lane * 64] != 0);
        nt = bal ? (int)__ffsll(bal) - 1 : 8;
    }
    const int ct  = min((int)blockIdx.y, nt - 1);
    const int tlo = max(0, ct - 1);
    const int thi = min(nt - 1, ct + 1);

    // ---- prologue: reg-load Q, K[tlo], V[tlo]; swizzled ds_write of Q, K ----
    int r_[2], cs_[2];
    u16x8 qreg[2], kreg[2], vreg[2];
    #pragma unroll
    for (int p = 0; p < 2; ++p) {
        int s = tid + p * 256;
        r_[p] = s >> 3; cs_[p] = s & 7;
        qreg[p] = *(const u16x8*)(pkv + qbase  + (size_t)r_[p] * 1536 + cs_[p] * 8);
        kreg[p] = *(const u16x8*)(pkv + kbaseg + (size_t)(tlo * 64 + r_[p]) * 1536 + cs_[p] * 8);
        vreg[p] = *(const u16x8*)(vpT + vbaseg + (size_t)r_[p] * NT + tlo * 64 + cs_[p] * 8);
    }
    #pragma unroll
    for (int p = 0; p < 2; ++p) {
        *(u16x8*)(QP + SWU(r_[p], cs_[p])) = qreg[p];
        *(u16x8*)(Kl + SWU(r_[p], cs_[p])) = kreg[p];
    }
    // rpe_k -> rpk (in Vl space): 264 chunks, strided (264 > 256 threads!)
    for (int idx = tid; idx < 264; idx += 256) {
        int r = idx >> 3, c = idx & 7;
        float4 f0 = *(const float4*)&rpe[r * 128 + c * 8];
        float4 f1 = *(const float4*)&rpe[r * 128 + c * 8 + 4];
        u16x8 vv;
        vv[0]=f2b(f0.x); vv[1]=f2b(f0.y); vv[2]=f2b(f0.z); vv[3]=f2b(f0.w);
        vv[4]=f2b(f1.x); vv[5]=f2b(f1.y); vv[6]=f2b(f1.z); vv[7]=f2b(f1.w);
        *(u16x8*)(rpk + SWU(r, c)) = vv;
    }
    if (tid < 120) {   // zero rows 33..47
        u16x8 vv = {0,0,0,0,0,0,0,0};
        *(u16x8*)(rpk + (((33 + (tid >> 3)) * 8) + (tid & 7)) * 8) = vv;
    }
    if (tid < 64) {
        float md = mD[b * NT + q0 + tid];
        inv2s[tid] = 2.f * LOG2E / (md * md);
    }
    for (int i = tid; i < 64 * 34; i += 256) wbufl[i] = 0.f;
    __syncthreads();                                // (P0)

    // persistent Q A-frags (QP becomes Pl afterwards)
    bf16x8 aq0 = *(const bf16x8*)(QP + SWU(wq0 + fr, fq));
    bf16x8 aq1 = *(const bf16x8*)(QP + SWU(wq0 + fr, 4 + fq));

    // qdr[q][rd] = q . rpe_k[rd] via MFMA (reads rpk in Vl space)
    {
        f32x4 qd[3] = {};
        #pragma unroll
        for (int nf = 0; nf < 3; ++nf) {
            bf16x8 b0 = *(const bf16x8*)(rpk + SWU(nf * 16 + fr, fq));
            bf16x8 b1 = *(const bf16x8*)(rpk + SWU(nf * 16 + fr, 4 + fq));
            qd[nf] = __builtin_amdgcn_mfma_f32_16x16x32_bf16(aq0, b0, qd[nf], 0, 0, 0);
            qd[nf] = __builtin_amdgcn_mfma_f32_16x16x32_bf16(aq1, b1, qd[nf], 0, 0, 0);
        }
        #pragma unroll
        for (int nf = 0; nf < 3; ++nf) {
            int rd = nf * 16 + fr;
            if (rd < 33) {
                #pragma unroll
                for (int r = 0; r < 4; ++r)
                    qdrl[(wq0 + fq * 4 + r) * 36 + rd] = f2b(qd[nf][r]);
            }
        }
    }
    __syncthreads();                                // (P1) qdr done; rpk dead
    // V[tlo] ds_write into Vl (visible at first iter's barrier (1))
    #pragma unroll
    for (int p = 0; p < 2; ++p)
        *(u16x8*)(Vl + SWU(r_[p], cs_[p])) = vreg[p];

    f32x4 O[4] = {};
    float m2[4] = {NEGINF, NEGINF, NEGINF, NEGINF};
    float li[4] = {};

    for (int t = tlo; t <= thi; ++t) {
        const int kb = t * 64;
        const bool pre = (t < thi);
        u16x8 kreg2[2], vreg2[2];
        if (pre) {
            const int kn = kb + 64;
            #pragma unroll
            for (int p = 0; p < 2; ++p) {
                kreg2[p] = *(const u16x8*)(pkv + kbaseg + (size_t)(kn + r_[p]) * 1536 + cs_[p] * 8);
                vreg2[p] = *(const u16x8*)(vpT + vbaseg + (size_t)r_[p] * NT + kn + cs_[p] * 8);
            }
        }
        int mk[4];
        #pragma unroll
        for (int nf = 0; nf < 4; ++nf) mk[nf] = mask[b * NT + kb + nf * 16 + fr];

        // ---- QK^T ----
        f32x4 s_[4] = {};
        #pragma unroll
        for (int nf = 0; nf < 4; ++nf) {
            bf16x8 b0 = *(const bf16x8*)(Kl + SWU(nf * 16 + fr, fq));
            bf16x8 b1 = *(const bf16x8*)(Kl + SWU(nf * 16 + fr, 4 + fq));
            s_[nf] = __builtin_amdgcn_mfma_f32_16x16x32_bf16(aq0, b0, s_[nf], 0, 0, 0);
            s_[nf] = __builtin_amdgcn_mfma_f32_16x16x32_bf16(aq1, b1, s_[nf], 0, 0, 0);
        }
        // ---- softmax (log2 domain) ----
        const bool leftfar  = (kb + 79 <= q0);
        const bool rightfar = (kb >= q0 + 79);
        const bool mid = !leftfar && !rightfar;

        float p_[4][4], alpha[4], rsum_[4], ls_[4], rs_[4];
        #pragma unroll
        for (int r = 0; r < 4; ++r) {
            const int lq = wq0 + fq * 4 + r;
            const int qg = q0 + lq;
            const float iv = inv2s[lq];
            const float qf = leftfar ? b2f(qdrl[lq * 36]) : (rightfar ? b2f(qdrl[lq * 36 + 32]) : 0.f);
            float mx = NEGINF;
            #pragma unroll
            for (int nf = 0; nf < 4; ++nf) {
                const int kg = kb + nf * 16 + fr;
                float sc;
                if (mk[nf]) sc = NEGINF;
                else {
                    float qr = mid ? b2f(qdrl[lq * 36 + (min(max(kg - qg, -MAXR), MAXR) + MAXR)]) : qf;
                    float fd = (float)(qg - kg);
                    sc = (s_[nf][r] + qr) * C1F - fd * fd * iv;
                }
                p_[r][nf] = sc;
                mx = fmaxf(mx, sc);
            }
            mx = fmaxf(mx, __shfl_xor(mx, 1, 64));
            mx = fmaxf(mx, __shfl_xor(mx, 2, 64));
            mx = fmaxf(mx, __shfl_xor(mx, 4, 64));
            mx = fmaxf(mx, __shfl_xor(mx, 8, 64));
            float mn = fmaxf(m2[r], mx);
            alpha[r] = exp2_fast(m2[r] - mn);
            m2[r] = mn;
            float rsum = 0.f, ls = 0.f, rs = 0.f;
            #pragma unroll
            for (int nf = 0; nf < 4; ++nf) {
                float pv = exp2_fast(p_[r][nf] - mn);
                p_[r][nf] = pv;
                rsum += pv;
                if (mid) {
                    int kg = kb + nf * 16 + fr;
                    if (kg <= qg - MAXR) ls += pv;
                    else if (kg >= qg + MAXR) rs += pv;
                }
            }
            rsum += __shfl_xor(rsum, 1, 64); rsum += __shfl_xor(rsum, 2, 64);
            rsum += __shfl_xor(rsum, 4, 64); rsum += __shfl_xor(rsum, 8, 64);
            if (mid) {
                ls += __shfl_xor(ls, 1, 64); ls += __shfl_xor(ls, 2, 64);
                ls += __shfl_xor(ls, 4, 64); ls += __shfl_xor(ls, 8, 64);
                rs += __shfl_xor(rs, 1, 64); rs += __shfl_xor(rs, 2, 64);
                rs += __shfl_xor(rs, 4, 64); rs += __shfl_xor(rs, 8, 64);
            }
            li[r] = li[r] * alpha[r] + rsum;
            rsum_[r] = rsum; ls_[r] = ls; rs_[r] = rs;
        }
        // O rescale
        #pragma unroll
        for (int nf = 0; nf < 4; ++nf) {
            O[nf][0] *= alpha[0]; O[nf][1] *= alpha[1];
            O[nf][2] *= alpha[2]; O[nf][3] *= alpha[3];
        }
        // wbuf rescale + tile contributions
        #pragma unroll
        for (int r = 0; r < 4; ++r) {
            int lq = wq0 + fq * 4 + r;
            if (alpha[r] != 1.f) {
                for (int c = fr; c < 33; c += 16) wbufl[lq * 34 + c] *= alpha[r];
            }
        }
        if (fr == 0) {
            #pragma unroll
            for (int r = 0; r < 4; ++r) {
                int lq = wq0 + fq * 4 + r;
                if (leftfar)       wbufl[lq * 34]      += rsum_[r];
                else if (rightfar) wbufl[lq * 34 + 32] += rsum_[r];
                else { wbufl[lq * 34] += ls_[r]; wbufl[lq * 34 + 32] += rs_[r]; }
            }
        }
        if (mid) {
            #pragma unroll
            for (int r = 0; r < 4; ++r) {
                int lq = wq0 + fq * 4 + r, qg = q0 + lq;
                #pragma unroll
                for (int nf = 0; nf < 4; ++nf) {
                    int d = kb + nf * 16 + fr - qg;
                    if (d > -MAXR && d < MAXR) wbufl[lq * 34 + d + MAXR] += p_[r][nf];
                }
            }
        }
        // ---- P -> bf16 LDS (swizzled, in QP space) ----
        #pragma unroll
        for (int r = 0; r < 4; ++r) {
            int lq = wq0 + fq * 4 + r;
            #pragma unroll
            for (int nf = 0; nf < 4; ++nf) {
                int k = nf * 16 + fr;
                QP[lq * 64 + (((k >> 3) ^ (lq & 7)) << 3) + (k & 7)] = f2b(p_[r][nf]);
            }
        }
        __syncthreads();    // (1) P + V(t) visible; all QK reads of Kl done
        // K(t+1) into Kl (QK done; PV doesn't touch Kl)
        if (pre) {
            #pragma unroll
            for (int p = 0; p < 2; ++p)
                *(u16x8*)(Kl + SWU(r_[p], cs_[p])) = kreg2[p];
        }
        // ---- PV ----
        bf16x8 ap0 = *(const bf16x8*)(QP + SWU(wq0 + fr, fq));
        bf16x8 ap1 = *(const bf16x8*)(QP + SWU(wq0 + fr, 4 + fq));
        #pragma unroll
        for (int nf = 0; nf < 4; ++nf) {
            bf16x8 v0 = *(const bf16x8*)(Vl + SWU(nf * 16 + fr, fq));
            bf16x8 v1 = *(const bf16x8*)(Vl + SWU(nf * 16 + fr, 4 + fq));
            O[nf] = __builtin_amdgcn_mfma_f32_16x16x32_bf16(ap0, v0, O[nf], 0, 0, 0);
            O[nf] = __builtin_amdgcn_mfma_f32_16x16x32_bf16(ap1, v1, O[nf], 0, 0, 0);
        }
        __syncthreads();    // (2) PV reads of Vl/QP done; K(t+1) visible
        // V(t+1) into Vl (visible at next iter's barrier (1))
        if (pre) {
            #pragma unroll
            for (int p = 0; p < 2; ++p)
                *(u16x8*)(Vl + SWU(r_[p], cs_[p])) = vreg2[p];
        }
    }

    // ---- epilogue: rpe_v (bf16, in Kl space) via wbuf buckets ----
    for (int idx = tid; idx < 264; idx += 256) {   // strided: 264 > 256
        int r = idx >> 3, c = idx & 7;
        float4 f0 = *(const float4*)&rpe[r * 128 + 64 + c * 8];
        float4 f1 = *(const float4*)&rpe[r * 128 + 64 + c * 8 + 4];
        u16x8 vv;
        vv[0]=f2b(f0.x); vv[1]=f2b(f0.y); vv[2]=f2b(f0.z); vv[3]=f2b(f0.w);
        vv[4]=f2b(f1.x); vv[5]=f2b(f1.y); vv[6]=f2b(f1.z); vv[7]=f2b(f1.w);
        *(u16x8*)(rvl16 + (r * 8 + c) * 8) = vv;
    }
    __syncthreads();
    for (int rd = 0; rd < 33; ++rd) {
        float rvv[4];
        #pragma unroll
        for (int nf = 0; nf < 4; ++nf) rvv[nf] = b2f(rvl16[rd * 64 + nf * 16 + fr]);
        #pragma unroll
        for (int r = 0; r < 4; ++r) {
            float wv = wbufl[(wq0 + fq * 4 + r) * 34 + rd];
            #pragma unroll
            for (int nf = 0; nf < 4; ++nf) O[nf][r] += wv * rvv[nf];
        }
    }
    float invl[4];
    #pragma unroll
    for (int r = 0; r < 4; ++r) invl[r] = 1.f / li[r];
    #pragma unroll
    for (int r = 0; r < 4; ++r) {
        int lq = wq0 + fq * 4 + r;
        #pragma unroll
        for (int nf = 0; nf < 4; ++nf)
            QP[lq * 64 + nf * 16 + fr] = f2b(O[nf][r] * invl[r]);   // linear bounce
    }
    __syncthreads();
    #pragma unroll
    for (int j = 0; j < 2; ++j) {
        int s = w * 128 + j * 64 + lane;
        int rr = s >> 3, c8 = s & 7;
        u16x8 vv = *(const u16x8*)(QP + rr * 64 + c8 * 8);
        *(u16x8*)&cxh[((size_t)(b*NT + q0 + rr)) * 512 + h * NHD + c8 * 8] = vv;
    }
}

// ---------------------------------------------------------------------------
extern "C" void kernel_launch(void* const* d_in, const int* in_sizes, int n_in,
                              void* d_out, int out_size, void* d_ws, size_t ws_size,
                              hipStream_t stream) {
    const float* key   = (const float*)d_in[0];
    const float* value = (const float*)d_in[1];
    const float* query = (const float*)d_in[2];
    const int*   mask  = (const int*)d_in[3];
    const float* Wq  = (const float*)d_in[4];
    const float* bq  = (const float*)d_in[5];
    const float* Wk  = (const float*)d_in[6];
    const float* bk  = (const float*)d_in[7];
    const float* Wv  = (const float*)d_in[8];
    const float* bv  = (const float*)d_in[9];
    const float* Wcq = (const float*)d_in[10];
    const float* Wck = (const float*)d_in[11];
    const float* Wcv = (const float*)d_in[12];
    const float* Wgq = (const float*)d_in[13];
    const float* bgq = (const float*)d_in[14];
    const float* Wgk = (const float*)d_in[15];
    const float* bgk = (const float*)d_in[16];
    const float* Wgv = (const float*)d_in[17];
    const float* bgv = (const float*)d_in[18];
    const float* WmD = (const float*)d_in[19];
    const float* bmD = (const float*)d_in[20];
    const float* rpe = (const float*)d_in[21];
    const float* Wo  = (const float*)d_in[22];
    const float* bo  = (const float*)d_in[23];
    float* out = (float*)d_out;

    const size_t NTOK = (size_t)NB * NT;            // 8192
    const size_t NE   = NTOK * NSZ;                 // 4,194,304
    const size_t NW   = (size_t)NSZ * NSZ;          // 262,144

    u16* ws16 = (u16*)d_ws;
    u16* qx   = ws16;                // bf16 inputs
    u16* kx   = qx + NE;
    u16* vx   = kx + NE;
    u16* pkv  = vx + NE;             // (8192, 1536) q|k|v
    u16* wcat = pkv + NTOK * 1536;   // 3 x (512,512)
    u16* woh  = wcat + 3 * NW;
    u16* vpT  = woh + NW;            // (16*8*64, 512)
    u16* cxh  = vpT + NE;            // (8192, 512)
    float* bcat = (float*)(cxh + NE);
    float* mDb  = bcat + 1536;

    cvt3_bf16<<<dim3((unsigned)(NE/8/256), 3), 256, 0, stream>>>(
        query, key, value, qx, kx, vx, (int)NE);
    cvt4_bf16<<<dim3((unsigned)(NW/8/256), 4), 256, 0, stream>>>(
        Wq, Wk, Wv, Wo, wcat, wcat + NW, wcat + 2*NW, woh, (int)NW);
    bcat_k<<<6, 256, 0, stream>>>(bq, bk, bv, bcat);

    gemm_qkv<<<dim3(64, 4, 3), 256, 0, stream>>>(qx, kx, vx, wcat, bcat, pkv);

    conv_gate_all<<<(int)(NTOK / 4), 256, 0, stream>>>(
        kx, pkv, Wcq, Wck, Wcv, Wgq, bgq, Wgk, bgk, Wgv, bgv, WmD, bmD, mDb);

    vtrans<<<dim3(8, 8, 16), 256, 0, stream>>>(pkv, vpT);

    attn_mfma<<<dim3(128, 8), 256, 0, stream>>>(pkv, vpT, mDb, mask, rpe, cxh);

    gemm_out<<<dim3(64, 4), 256, 0, stream>>>(cxh, woh, bo, out, (int)NTOK, NSZ, NSZ);
}

// Round 9
// 154.492 us; speedup vs baseline: 1.2846x; 1.0415x over previous
//
#include <hip/hip_runtime.h>
#include <math.h>

#define NB 16
#define NT 512
#define NSZ 512
#define NH 8
#define NHD 64
#define MAXR 16

#define C_D0 6.3f
#define C_STD 1.4f
#define C_GAMMA 2.0f

#define NEGINF (-1e30f)
#define LOG2E 1.4426950408889634f
#define C1F   0.18033688011112042f   // 0.125 * log2(e)

typedef unsigned short u16;
typedef __attribute__((ext_vector_type(8))) short bf16x8;
typedef __attribute__((ext_vector_type(4))) float f32x4;
typedef __attribute__((ext_vector_type(8))) unsigned short u16x8;

__device__ __forceinline__ u16 f2b(float f) {
    union { float f; unsigned int u; } c; c.f = f;
    unsigned int u = c.u + 0x7FFFu + ((c.u >> 16) & 1u);
    return (u16)(u >> 16);
}
__device__ __forceinline__ float b2f(u16 h) {
    union { unsigned int u; float f; } c; c.u = ((unsigned int)h) << 16;
    return c.f;
}

#if __has_builtin(__builtin_amdgcn_exp2f)
__device__ __forceinline__ float exp2_fast(float x) { return __builtin_amdgcn_exp2f(x); }
#else
__device__ __forceinline__ float exp2_fast(float x) { return exp2f(x); }
#endif

#define GL2LDS(gp, lp) __builtin_amdgcn_global_load_lds( \
    (const __attribute__((address_space(1))) void*)(gp), \
    (__attribute__((address_space(3))) void*)(lp), 16, 0, 0)

// swizzled u16-index of 16B chunk c in row r (row = 8 chunks = 64 bf16)
#define SWU(r, c) ((((r) * 8) + ((c) ^ ((r) & 7))) * 8)

// ---------------------------------------------------------------------------
// fp32 -> bf16 convert (weights only now)
// ---------------------------------------------------------------------------
__global__ __launch_bounds__(256) void cvt4_bf16(
    const float* __restrict__ s0, const float* __restrict__ s1,
    const float* __restrict__ s2, const float* __restrict__ s3,
    u16* __restrict__ d0, u16* __restrict__ d1,
    u16* __restrict__ d2, u16* __restrict__ d3, int n)
{
    const float* s; u16* d;
    switch (blockIdx.y) {
        case 0: s = s0; d = d0; break;
        case 1: s = s1; d = d1; break;
        case 2: s = s2; d = d2; break;
        default: s = s3; d = d3; break;
    }
    int i = (blockIdx.x * 256 + threadIdx.x) * 8;
    if (i >= n) return;
    float4 a = *(const float4*)&s[i];
    float4 b = *(const float4*)&s[i + 4];
    u16x8 v;
    v[0]=f2b(a.x); v[1]=f2b(a.y); v[2]=f2b(a.z); v[3]=f2b(a.w);
    v[4]=f2b(b.x); v[5]=f2b(b.y); v[6]=f2b(b.z); v[7]=f2b(b.w);
    *(u16x8*)&d[i] = v;
}

__global__ void bcat_k(const float* __restrict__ bq, const float* __restrict__ bk,
                       const float* __restrict__ bv, float* __restrict__ bc)
{
    int i = blockIdx.x * 256 + threadIdx.x;
    if (i >= 1536) return;
    bc[i] = i < 512 ? bq[i] : (i < 1024 ? bk[i - 512] : bv[i - 1024]);
}

// ---------------------------------------------------------------------------
// QKV projections, z-batched. A is fp32 (raw inputs): register-staged with
// in-flight fp32->bf16 convert (same f2b rounding as the old cvt3 path).
// ---------------------------------------------------------------------------
__global__ __launch_bounds__(256) void gemm_qkv(
    const float* __restrict__ A0, const float* __restrict__ A1, const float* __restrict__ A2,
    const u16* __restrict__ Wc, const float* __restrict__ bc,
    u16* __restrict__ pkv)
{
    __shared__ u16 Al[128 * 32];
    __shared__ u16 Bl[128 * 32];
    const int z = blockIdx.z;
    const float* A = z == 0 ? A0 : (z == 1 ? A1 : A2);
    const u16* W = Wc + (size_t)z * NSZ * NSZ;
    const float* bias = bc + z * NSZ;
    const int tid = threadIdx.x;
    const int m0 = blockIdx.x * 128;
    const int n0 = blockIdx.y * 128;
    const int w = tid >> 6, lane = tid & 63;
    const int wm = (w >> 1) * 64, wn = (w & 1) * 64;
    const int fr = lane & 15, fk = lane >> 4;

    f32x4 acc[4][4] = {};
    for (int k0 = 0; k0 < NSZ; k0 += 32) {
        float4 a0[2], a1[2];
        #pragma unroll
        for (int p = 0; p < 2; ++p) {
            int s = tid + p * 256;
            int row = s >> 2, cb = s & 3;
            const float* ga = &A[(size_t)(m0 + row) * NSZ + k0 + cb * 8];
            a0[p] = *(const float4*)ga;
            a1[p] = *(const float4*)(ga + 4);
            GL2LDS(&W[(size_t)(n0 + row) * NSZ + k0 + cb * 8], &Bl[s * 8]);
        }
        #pragma unroll
        for (int p = 0; p < 2; ++p) {
            int s = tid + p * 256;
            u16x8 v;
            v[0]=f2b(a0[p].x); v[1]=f2b(a0[p].y); v[2]=f2b(a0[p].z); v[3]=f2b(a0[p].w);
            v[4]=f2b(a1[p].x); v[5]=f2b(a1[p].y); v[6]=f2b(a1[p].z); v[7]=f2b(a1[p].w);
            *(u16x8*)&Al[s * 8] = v;
        }
        __syncthreads();
        bf16x8 af[4], bfr[4];
        #pragma unroll
        for (int mf = 0; mf < 4; ++mf)
            af[mf] = *(const bf16x8*)&Al[(wm + mf * 16 + fr) * 32 + fk * 8];
        #pragma unroll
        for (int nf = 0; nf < 4; ++nf)
            bfr[nf] = *(const bf16x8*)&Bl[(wn + nf * 16 + fr) * 32 + fk * 8];
        #pragma unroll
        for (int mf = 0; mf < 4; ++mf)
            #pragma unroll
            for (int nf = 0; nf < 4; ++nf)
                acc[mf][nf] = __builtin_amdgcn_mfma_f32_16x16x32_bf16(
                    af[mf], bfr[nf], acc[mf][nf], 0, 0, 0);
        __syncthreads();
    }
    #pragma unroll
    for (int mf = 0; mf < 4; ++mf) {
        #pragma unroll
        for (int nf = 0; nf < 4; ++nf) {
            int col = n0 + wn + nf * 16 + fr;
            float bv = bias[col];
            #pragma unroll
            for (int r = 0; r < 4; ++r) {
                int rowg = m0 + wm + mf * 16 + fk * 4 + r;
                pkv[(size_t)rowg * 1536 + z * 512 + col] = f2b(acc[mf][nf][r] + bv);
            }
        }
    }
}

// ---------------------------------------------------------------------------
// Output projection (fp32 out)
// ---------------------------------------------------------------------------
__global__ __launch_bounds__(256) void gemm_out(
    const u16* __restrict__ A, const u16* __restrict__ W,
    const float* __restrict__ bias, float* __restrict__ Cout, int M, int N, int K)
{
    __shared__ u16 Al[128 * 32];
    __shared__ u16 Bl[128 * 32];
    const int tid = threadIdx.x;
    const int m0 = blockIdx.x * 128;
    const int n0 = blockIdx.y * 128;
    const int w = tid >> 6, lane = tid & 63;
    const int wm = (w >> 1) * 64, wn = (w & 1) * 64;
    const int fr = lane & 15, fk = lane >> 4;

    f32x4 acc[4][4] = {};
    for (int k0 = 0; k0 < K; k0 += 32) {
        #pragma unroll
        for (int p = 0; p < 2; ++p) {
            int s = tid + p * 256;
            int row = s >> 2, cb = s & 3;
            GL2LDS(&A[(size_t)(m0 + row) * K + k0 + cb * 8], &Al[s * 8]);
            GL2LDS(&W[(size_t)(n0 + row) * K + k0 + cb * 8], &Bl[s * 8]);
        }
        __syncthreads();
        bf16x8 af[4], bfr[4];
        #pragma unroll
        for (int mf = 0; mf < 4; ++mf)
            af[mf] = *(const bf16x8*)&Al[(wm + mf * 16 + fr) * 32 + fk * 8];
        #pragma unroll
        for (int nf = 0; nf < 4; ++nf)
            bfr[nf] = *(const bf16x8*)&Bl[(wn + nf * 16 + fr) * 32 + fk * 8];
        #pragma unroll
        for (int mf = 0; mf < 4; ++mf)
            #pragma unroll
            for (int nf = 0; nf < 4; ++nf)
                acc[mf][nf] = __builtin_amdgcn_mfma_f32_16x16x32_bf16(
                    af[mf], bfr[nf], acc[mf][nf], 0, 0, 0);
        __syncthreads();
    }
    #pragma unroll
    for (int mf = 0; mf < 4; ++mf) {
        #pragma unroll
        for (int nf = 0; nf < 4; ++nf) {
            int col = n0 + wn + nf * 16 + fr;
            float bv = bias[col];
            #pragma unroll
            for (int r = 0; r < 4; ++r) {
                int rowg = m0 + wm + mf * 16 + fk * 4 + r;
                Cout[(size_t)rowg * N + col] = acc[mf][nf][r] + bv;
            }
        }
    }
}

// ---------------------------------------------------------------------------
// Fused 3x depthwise conv1d(k=5) + 3 scalar gates + mD. xn is raw fp32 key.
// Wave-per-token: 256 thr = 4 waves; 8 channels/lane; shfl reductions.
// ---------------------------------------------------------------------------
__global__ __launch_bounds__(256) void conv_gate_all(
    const float* __restrict__ xn, u16* __restrict__ pkv,
    const float* __restrict__ Wcq, const float* __restrict__ Wck, const float* __restrict__ Wcv,
    const float* __restrict__ Wgq, const float* __restrict__ bgq,
    const float* __restrict__ Wgk, const float* __restrict__ bgk,
    const float* __restrict__ Wgv, const float* __restrict__ bgv,
    const float* __restrict__ WmD, const float* __restrict__ bmD,
    float* __restrict__ mD)
{
    const int w = threadIdx.x >> 6, lane = threadIdx.x & 63;
    const int bt = blockIdx.x * 4 + w;
    const int b = bt >> 9, tpos = bt & (NT - 1);
    const int c0 = lane * 8;

    float x[5][8];
    #pragma unroll
    for (int j = 0; j < 5; ++j) {
        int tt = tpos + j - 2;
        if (tt >= 0 && tt < NT) {
            const float4* xp = (const float4*)&xn[((size_t)(b*NT + tt))*NSZ + c0];
            float4 u0 = xp[0], u1 = xp[1];
            x[j][0]=u0.x; x[j][1]=u0.y; x[j][2]=u0.z; x[j][3]=u0.w;
            x[j][4]=u1.x; x[j][5]=u1.y; x[j][6]=u1.z; x[j][7]=u1.w;
        } else {
            #pragma unroll
            for (int i = 0; i < 8; ++i) x[j][i] = 0.f;
        }
    }
    const size_t rb = (size_t)bt * 1536;
    u16x8 q8 = *(const u16x8*)&pkv[rb + c0];
    u16x8 k8 = *(const u16x8*)&pkv[rb + 512 + c0];
    u16x8 v8 = *(const u16x8*)&pkv[rb + 1024 + c0];

    float aq[8], ak[8], av[8];
    float sq = 0.f, sk = 0.f, sv = 0.f;
    #pragma unroll
    for (int i = 0; i < 8; ++i) {
        int c = c0 + i;
        float a0 = 0.f, a1 = 0.f, a2 = 0.f;
        #pragma unroll
        for (int j = 0; j < 5; ++j) {
            a0 += x[j][i] * Wcq[c*5 + j];
            a1 += x[j][i] * Wck[c*5 + j];
            a2 += x[j][i] * Wcv[c*5 + j];
        }
        aq[i] = a0; ak[i] = a1; av[i] = a2;
        sq += b2f(q8[i]) * Wgq[c] + a0 * Wgq[512 + c];
        sk += b2f(k8[i]) * Wgk[c] + a1 * Wgk[512 + c];
        sv += b2f(v8[i]) * Wgv[c] + a2 * Wgv[512 + c];
    }
    #pragma unroll
    for (int o = 1; o < 64; o <<= 1) {
        sq += __shfl_xor(sq, o, 64);
        sk += __shfl_xor(sk, o, 64);
        sv += __shfl_xor(sv, o, 64);
    }
    float gq = 1.f / (1.f + expf(-(sq + bgq[0])));
    float gk = 1.f / (1.f + expf(-(sk + bgk[0])));
    float gv = 1.f / (1.f + expf(-(sv + bgv[0])));

    u16x8 oq8, ok8, ov8;
    float smd = 0.f;
    #pragma unroll
    for (int i = 0; i < 8; ++i) {
        float oq = (1.f - gq) * b2f(q8[i]) + gq * aq[i];
        oq8[i] = f2b(oq);
        ok8[i] = f2b((1.f - gk) * b2f(k8[i]) + gk * ak[i]);
        ov8[i] = f2b((1.f - gv) * b2f(v8[i]) + gv * av[i]);
        smd += oq * WmD[c0 + i];
    }
    *(u16x8*)&pkv[rb + c0]        = oq8;
    *(u16x8*)&pkv[rb + 512 + c0]  = ok8;
    *(u16x8*)&pkv[rb + 1024 + c0] = ov8;
    #pragma unroll
    for (int o = 1; o < 64; o <<= 1) smd += __shfl_xor(smd, o, 64);
    if (lane == 0)
        mD[bt] = C_D0 + 2.f * C_STD * tanhf((smd + bmD[0]) / C_GAMMA);
}

// ---------------------------------------------------------------------------
// V transpose: pkv v-section (b,t,h*64+d) -> vpT[(b*8+h)*64+d][t]
// ---------------------------------------------------------------------------
__global__ __launch_bounds__(256) void vtrans(
    const u16* __restrict__ pkv, u16* __restrict__ vpT)
{
    __shared__ u16 lt[64][72];
    const int t0 = blockIdx.x * 64;
    const int h = blockIdx.y, b = blockIdx.z;
    const int tid = threadIdx.x;
    #pragma unroll
    for (int p = 0; p < 2; ++p) {
        int s = tid + p * 256;
        int t = s >> 3, c8 = s & 7;
        u16x8 v = *(const u16x8*)&pkv[((size_t)(b*NT + t0 + t))*1536 + 1024 + h*NHD + c8*8];
        *(u16x8*)&lt[t][c8 * 8] = v;
    }
    __syncthreads();
    #pragma unroll
    for (int p = 0; p < 2; ++p) {
        int s = tid + p * 256;
        int d = s >> 3, c8 = s & 7;
        u16x8 o;
        #pragma unroll
        for (int j = 0; j < 8; ++j) o[j] = lt[c8 * 8 + j][d];
        *(u16x8*)&vpT[((size_t)((b*NH + h)*NHD + d))*NT + t0 + c8*8] = o;
    }
}

// ---------------------------------------------------------------------------
// MFMA flash attention — windowed + MFMA epilogue.
// R9 change: the rpe_v epilogue (O += wbuf @ rpe_v) runs as 8 MFMAs instead
// of a 33-iter VALU loop: wbuf->bf16 wA in QP, rpe_v^T in Vl (LDS transpose).
// ---------------------------------------------------------------------------
__global__ __launch_bounds__(256) void attn_mfma(
    const u16* __restrict__ pkv, const u16* __restrict__ vpT,
    const float* __restrict__ mD, const int* __restrict__ mask,
    const float* __restrict__ rpe, u16* __restrict__ cxh)
{
    __shared__ __align__(16) char smem[38144];
    u16*  QP    = (u16*)(smem);              // Q (prologue), P (loop), wA (epi)
    u16*  Kl    = (u16*)(smem + 8192);       // K tile; epi: rvl linear / out-bounce
    u16*  Vl    = (u16*)(smem + 16384);      // V tile; prologue: rpk; epi: rvT
    u16*  rpk   = (u16*)(smem + 16384);
    u16*  rvl16 = (u16*)(smem + 8192);
    u16*  qdrl  = (u16*)(smem + 24576);      // [64][36] bf16
    float* wbufl= (float*)(smem + 29184);    // [64][34] fp32 (col 33 stays 0)
    float* inv2s= (float*)(smem + 37888);    // [64]

    const int tid  = threadIdx.x;
    const int lane = tid & 63;
    const int w    = tid >> 6;
    const int wq0  = w * 16;
    const int fr   = lane & 15;
    const int fq   = lane >> 4;
    const int b    = blockIdx.x >> 3;
    const int h    = blockIdx.x & 7;
    const int q0   = blockIdx.y * 64;

    const size_t qbase  = ((size_t)(b*NT + q0)) * 1536 + h * NHD;
    const size_t kbaseg = ((size_t)b * NT) * 1536 + 512 + h * NHD;
    const size_t vbaseg = ((size_t)((b*NH + h) * NHD)) * NT;

    // ---- tile window: nt from mask ballot, then clamp to diagonal +-1 ----
    int nt;
    {
        unsigned long long bal = __ballot(lane < 8 && mask[b * NT + lane * 64] != 0);
        nt = bal ? (int)__ffsll(bal) - 1 : 8;
    }
    const int ct  = min((int)blockIdx.y, nt - 1);
    const int tlo = max(0, ct - 1);
    const int thi = min(nt - 1, ct + 1);

    // ---- prologue: reg-load Q, K[tlo], V[tlo]; swizzled ds_write of Q, K ----
    int r_[2], cs_[2];
    u16x8 qreg[2], kreg[2], vreg[2];
    #pragma unroll
    for (int p = 0; p < 2; ++p) {
        int s = tid + p * 256;
        r_[p] = s >> 3; cs_[p] = s & 7;
        qreg[p] = *(const u16x8*)(pkv + qbase  + (size_t)r_[p] * 1536 + cs_[p] * 8);
        kreg[p] = *(const u16x8*)(pkv + kbaseg + (size_t)(tlo * 64 + r_[p]) * 1536 + cs_[p] * 8);
        vreg[p] = *(const u16x8*)(vpT + vbaseg + (size_t)r_[p] * NT + tlo * 64 + cs_[p] * 8);
    }
    #pragma unroll
    for (int p = 0; p < 2; ++p) {
        *(u16x8*)(QP + SWU(r_[p], cs_[p])) = qreg[p];
        *(u16x8*)(Kl + SWU(r_[p], cs_[p])) = kreg[p];
    }
    // rpe_k -> rpk (in Vl space): 264 chunks, strided (264 > 256 threads!)
    for (int idx = tid; idx < 264; idx += 256) {
        int r = idx >> 3, c = idx & 7;
        float4 f0 = *(const float4*)&rpe[r * 128 + c * 8];
        float4 f1 = *(const float4*)&rpe[r * 128 + c * 8 + 4];
        u16x8 vv;
        vv[0]=f2b(f0.x); vv[1]=f2b(f0.y); vv[2]=f2b(f0.z); vv[3]=f2b(f0.w);
        vv[4]=f2b(f1.x); vv[5]=f2b(f1.y); vv[6]=f2b(f1.z); vv[7]=f2b(f1.w);
        *(u16x8*)(rpk + SWU(r, c)) = vv;
    }
    if (tid < 120) {   // zero rows 33..47
        u16x8 vv = {0,0,0,0,0,0,0,0};
        *(u16x8*)(rpk + (((33 + (tid >> 3)) * 8) + (tid & 7)) * 8) = vv;
    }
    if (tid < 64) {
        float md = mD[b * NT + q0 + tid];
        inv2s[tid] = 2.f * LOG2E / (md * md);
    }
    for (int i = tid; i < 64 * 34; i += 256) wbufl[i] = 0.f;
    __syncthreads();                                // (P0)

    // persistent Q A-frags (QP becomes Pl afterwards)
    bf16x8 aq0 = *(const bf16x8*)(QP + SWU(wq0 + fr, fq));
    bf16x8 aq1 = *(const bf16x8*)(QP + SWU(wq0 + fr, 4 + fq));

    // qdr[q][rd] = q . rpe_k[rd] via MFMA (reads rpk in Vl space)
    {
        f32x4 qd[3] = {};
        #pragma unroll
        for (int nf = 0; nf < 3; ++nf) {
            bf16x8 b0 = *(const bf16x8*)(rpk + SWU(nf * 16 + fr, fq));
            bf16x8 b1 = *(const bf16x8*)(rpk + SWU(nf * 16 + fr, 4 + fq));
            qd[nf] = __builtin_amdgcn_mfma_f32_16x16x32_bf16(aq0, b0, qd[nf], 0, 0, 0);
            qd[nf] = __builtin_amdgcn_mfma_f32_16x16x32_bf16(aq1, b1, qd[nf], 0, 0, 0);
        }
        #pragma unroll
        for (int nf = 0; nf < 3; ++nf) {
            int rd = nf * 16 + fr;
            if (rd < 33) {
                #pragma unroll
                for (int r = 0; r < 4; ++r)
                    qdrl[(wq0 + fq * 4 + r) * 36 + rd] = f2b(qd[nf][r]);
            }
        }
    }
    __syncthreads();                                // (P1) qdr done; rpk dead
    // V[tlo] ds_write into Vl (visible at first iter's barrier (1))
    #pragma unroll
    for (int p = 0; p < 2; ++p)
        *(u16x8*)(Vl + SWU(r_[p], cs_[p])) = vreg[p];

    f32x4 O[4] = {};
    float m2[4] = {NEGINF, NEGINF, NEGINF, NEGINF};
    float li[4] = {};

    for (int t = tlo; t <= thi; ++t) {
        const int kb = t * 64;
        const bool pre = (t < thi);
        u16x8 kreg2[2], vreg2[2];
        if (pre) {
            const int kn = kb + 64;
            #pragma unroll
            for (int p = 0; p < 2; ++p) {
                kreg2[p] = *(const u16x8*)(pkv + kbaseg + (size_t)(kn + r_[p]) * 1536 + cs_[p] * 8);
                vreg2[p] = *(const u16x8*)(vpT + vbaseg + (size_t)r_[p] * NT + kn + cs_[p] * 8);
            }
        }
        int mk[4];
        #pragma unroll
        for (int nf = 0; nf < 4; ++nf) mk[nf] = mask[b * NT + kb + nf * 16 + fr];

        // ---- QK^T ----
        f32x4 s_[4] = {};
        #pragma unroll
        for (int nf = 0; nf < 4; ++nf) {
            bf16x8 b0 = *(const bf16x8*)(Kl + SWU(nf * 16 + fr, fq));
            bf16x8 b1 = *(const bf16x8*)(Kl + SWU(nf * 16 + fr, 4 + fq));
            s_[nf] = __builtin_amdgcn_mfma_f32_16x16x32_bf16(aq0, b0, s_[nf], 0, 0, 0);
            s_[nf] = __builtin_amdgcn_mfma_f32_16x16x32_bf16(aq1, b1, s_[nf], 0, 0, 0);
        }
        // ---- softmax (log2 domain) ----
        const bool leftfar  = (kb + 79 <= q0);
        const bool rightfar = (kb >= q0 + 79);
        const bool mid = !leftfar && !rightfar;

        float p_[4][4], alpha[4], rsum_[4], ls_[4], rs_[4];
        #pragma unroll
        for (int r = 0; r < 4; ++r) {
            const int lq = wq0 + fq * 4 + r;
            const int qg = q0 + lq;
            const float iv = inv2s[lq];
            const float qf = leftfar ? b2f(qdrl[lq * 36]) : (rightfar ? b2f(qdrl[lq * 36 + 32]) : 0.f);
            float mx = NEGINF;
            #pragma unroll
            for (int nf = 0; nf < 4; ++nf) {
                const int kg = kb + nf * 16 + fr;
                float sc;
                if (mk[nf]) sc = NEGINF;
                else {
                    float qr = mid ? b2f(qdrl[lq * 36 + (min(max(kg - qg, -MAXR), MAXR) + MAXR)]) : qf;
                    float fd = (float)(qg - kg);
                    sc = (s_[nf][r] + qr) * C1F - fd * fd * iv;
                }
                p_[r][nf] = sc;
                mx = fmaxf(mx, sc);
            }
            mx = fmaxf(mx, __shfl_xor(mx, 1, 64));
            mx = fmaxf(mx, __shfl_xor(mx, 2, 64));
            mx = fmaxf(mx, __shfl_xor(mx, 4, 64));
            mx = fmaxf(mx, __shfl_xor(mx, 8, 64));
            float mn = fmaxf(m2[r], mx);
            alpha[r] = exp2_fast(m2[r] - mn);
            m2[r] = mn;
            float rsum = 0.f, ls = 0.f, rs = 0.f;
            #pragma unroll
            for (int nf = 0; nf < 4; ++nf) {
                float pv = exp2_fast(p_[r][nf] - mn);
                p_[r][nf] = pv;
                rsum += pv;
                if (mid) {
                    int kg = kb + nf * 16 + fr;
                    if (kg <= qg - MAXR) ls += pv;
                    else if (kg >= qg + MAXR) rs += pv;
                }
            }
            rsum += __shfl_xor(rsum, 1, 64); rsum += __shfl_xor(rsum, 2, 64);
            rsum += __shfl_xor(rsum, 4, 64); rsum += __shfl_xor(rsum, 8, 64);
            if (mid) {
                ls += __shfl_xor(ls, 1, 64); ls += __shfl_xor(ls, 2, 64);
                ls += __shfl_xor(ls, 4, 64); ls += __shfl_xor(ls, 8, 64);
                rs += __shfl_xor(rs, 1, 64); rs += __shfl_xor(rs, 2, 64);
                rs += __shfl_xor(rs, 4, 64); rs += __shfl_xor(rs, 8, 64);
            }
            li[r] = li[r] * alpha[r] + rsum;
            rsum_[r] = rsum; ls_[r] = ls; rs_[r] = rs;
        }
        // O rescale
        #pragma unroll
        for (int nf = 0; nf < 4; ++nf) {
            O[nf][0] *= alpha[0]; O[nf][1] *= alpha[1];
            O[nf][2] *= alpha[2]; O[nf][3] *= alpha[3];
        }
        // wbuf rescale + tile contributions
        #pragma unroll
        for (int r = 0; r < 4; ++r) {
            int lq = wq0 + fq * 4 + r;
            if (alpha[r] != 1.f) {
                for (int c = fr; c < 33; c += 16) wbufl[lq * 34 + c] *= alpha[r];
            }
        }
        if (fr == 0) {
            #pragma unroll
            for (int r = 0; r < 4; ++r) {
                int lq = wq0 + fq * 4 + r;
                if (leftfar)       wbufl[lq * 34]      += rsum_[r];
                else if (rightfar) wbufl[lq * 34 + 32] += rsum_[r];
                else { wbufl[lq * 34] += ls_[r]; wbufl[lq * 34 + 32] += rs_[r]; }
            }
        }
        if (mid) {
            #pragma unroll
            for (int r = 0; r < 4; ++r) {
                int lq = wq0 + fq * 4 + r, qg = q0 + lq;
                #pragma unroll
                for (int nf = 0; nf < 4; ++nf) {
                    int d = kb + nf * 16 + fr - qg;
                    if (d > -MAXR && d < MAXR) wbufl[lq * 34 + d + MAXR] += p_[r][nf];
                }
            }
        }
        // ---- P -> bf16 LDS (swizzled, in QP space) ----
        #pragma unroll
        for (int r = 0; r < 4; ++r) {
            int lq = wq0 + fq * 4 + r;
            #pragma unroll
            for (int nf = 0; nf < 4; ++nf) {
                int k = nf * 16 + fr;
                QP[lq * 64 + (((k >> 3) ^ (lq & 7)) << 3) + (k & 7)] = f2b(p_[r][nf]);
            }
        }
        __syncthreads();    // (1) P + V(t) visible; all QK reads of Kl done
        // K(t+1) into Kl (QK done; PV doesn't touch Kl)
        if (pre) {
            #pragma unroll
            for (int p = 0; p < 2; ++p)
                *(u16x8*)(Kl + SWU(r_[p], cs_[p])) = kreg2[p];
        }
        // ---- PV ----
        bf16x8 ap0 = *(const bf16x8*)(QP + SWU(wq0 + fr, fq));
        bf16x8 ap1 = *(const bf16x8*)(QP + SWU(wq0 + fr, 4 + fq));
        #pragma unroll
        for (int nf = 0; nf < 4; ++nf) {
            bf16x8 v0 = *(const bf16x8*)(Vl + SWU(nf * 16 + fr, fq));
            bf16x8 v1 = *(const bf16x8*)(Vl + SWU(nf * 16 + fr, 4 + fq));
            O[nf] = __builtin_amdgcn_mfma_f32_16x16x32_bf16(ap0, v0, O[nf], 0, 0, 0);
            O[nf] = __builtin_amdgcn_mfma_f32_16x16x32_bf16(ap1, v1, O[nf], 0, 0, 0);
        }
        __syncthreads();    // (2) PV reads of Vl/QP done; K(t+1) visible
        // V(t+1) into Vl (visible at next iter's barrier (1))
        if (pre) {
            #pragma unroll
            for (int p = 0; p < 2; ++p)
                *(u16x8*)(Vl + SWU(r_[p], cs_[p])) = vreg2[p];
        }
    }

    // ---- epilogue: O += wbuf @ rpe_v via MFMA ----
    // Stage rpe_v LINEAR [rd][d] bf16 into Kl; convert wbuf -> bf16 wA in QP.
    for (int idx = tid; idx < 264; idx += 256) {   // strided: 264 > 256
        int r = idx >> 3, c = idx & 7;
        float4 f0 = *(const float4*)&rpe[r * 128 + 64 + c * 8];
        float4 f1 = *(const float4*)&rpe[r * 128 + 64 + c * 8 + 4];
        u16x8 vv;
        vv[0]=f2b(f0.x); vv[1]=f2b(f0.y); vv[2]=f2b(f0.z); vv[3]=f2b(f0.w);
        vv[4]=f2b(f1.x); vv[5]=f2b(f1.y); vv[6]=f2b(f1.z); vv[7]=f2b(f1.w);
        *(u16x8*)(rvl16 + (r * 8 + c) * 8) = vv;
    }
    // wA[q][rd] bf16 swizzled into QP; cols 34..63 zero (col 33 already 0)
    #pragma unroll
    for (int p = 0; p < 2; ++p) {
        int r = r_[p], cs = cs_[p];
        u16x8 vv;
        #pragma unroll
        for (int j = 0; j < 8; ++j) {
            int col = cs * 8 + j;
            vv[j] = (col < 34) ? f2b(wbufl[r * 34 + col]) : (u16)0;
        }
        *(u16x8*)(QP + SWU(r, cs)) = vv;
    }
    __syncthreads();   // (E1) rvl + wA ready (wbuf reads complete)
    // Build rvT[d][rd] bf16 swizzled into Vl from linear rvl16
    #pragma unroll
    for (int p = 0; p < 2; ++p) {
        int d = r_[p], cs = cs_[p];
        u16x8 vv;
        #pragma unroll
        for (int j = 0; j < 8; ++j) {
            int rd = cs * 8 + j;
            vv[j] = (rd < 33) ? rvl16[rd * 64 + d] : (u16)0;
        }
        *(u16x8*)(Vl + SWU(d, cs)) = vv;
    }
    __syncthreads();   // (E2) rvT ready
    {
        bf16x8 aw0 = *(const bf16x8*)(QP + SWU(wq0 + fr, fq));
        bf16x8 aw1 = *(const bf16x8*)(QP + SWU(wq0 + fr, 4 + fq));
        #pragma unroll
        for (int nf = 0; nf < 4; ++nf) {
            bf16x8 b0 = *(const bf16x8*)(Vl + SWU(nf * 16 + fr, fq));
            bf16x8 b1 = *(const bf16x8*)(Vl + SWU(nf * 16 + fr, 4 + fq));
            O[nf] = __builtin_amdgcn_mfma_f32_16x16x32_bf16(aw0, b0, O[nf], 0, 0, 0);
            O[nf] = __builtin_amdgcn_mfma_f32_16x16x32_bf16(aw1, b1, O[nf], 0, 0, 0);
        }
    }
    float invl[4];
    #pragma unroll
    for (int r = 0; r < 4; ++r) invl[r] = 1.f / li[r];
    #pragma unroll
    for (int r = 0; r < 4; ++r) {
        int lq = wq0 + fq * 4 + r;
        #pragma unroll
        for (int nf = 0; nf < 4; ++nf)
            Kl[lq * 64 + nf * 16 + fr] = f2b(O[nf][r] * invl[r]);   // linear bounce
    }
    __syncthreads();   // (E3)
    #pragma unroll
    for (int j = 0; j < 2; ++j) {
        int s = w * 128 + j * 64 + lane;
        int rr = s >> 3, c8 = s & 7;
        u16x8 vv = *(const u16x8*)(Kl + rr * 64 + c8 * 8);
        *(u16x8*)&cxh[((size_t)(b*NT + q0 + rr)) * 512 + h * NHD + c8 * 8] = vv;
    }
}

// ---------------------------------------------------------------------------
extern "C" void kernel_launch(void* const* d_in, const int* in_sizes, int n_in,
                              void* d_out, int out_size, void* d_ws, size_t ws_size,
                              hipStream_t stream) {
    const float* key   = (const float*)d_in[0];
    const float* value = (const float*)d_in[1];
    const float* query = (const float*)d_in[2];
    const int*   mask  = (const int*)d_in[3];
    const float* Wq  = (const float*)d_in[4];
    const float* bq  = (const float*)d_in[5];
    const float* Wk  = (const float*)d_in[6];
    const float* bk  = (const float*)d_in[7];
    const float* Wv  = (const float*)d_in[8];
    const float* bv  = (const float*)d_in[9];
    const float* Wcq = (const float*)d_in[10];
    const float* Wck = (const float*)d_in[11];
    const float* Wcv = (const float*)d_in[12];
    const float* Wgq = (const float*)d_in[13];
    const float* bgq = (const float*)d_in[14];
    const float* Wgk = (const float*)d_in[15];
    const float* bgk = (const float*)d_in[16];
    const float* Wgv = (const float*)d_in[17];
    const float* bgv = (const float*)d_in[18];
    const float* WmD = (const float*)d_in[19];
    const float* bmD = (const float*)d_in[20];
    const float* rpe = (const float*)d_in[21];
    const float* Wo  = (const float*)d_in[22];
    const float* bo  = (const float*)d_in[23];
    float* out = (float*)d_out;

    const size_t NTOK = (size_t)NB * NT;            // 8192
    const size_t NE   = NTOK * NSZ;                 // 4,194,304
    const size_t NW   = (size_t)NSZ * NSZ;          // 262,144

    u16* ws16 = (u16*)d_ws;
    u16* pkv  = ws16;                // (8192, 1536) q|k|v
    u16* wcat = pkv + NTOK * 1536;   // 3 x (512,512)
    u16* woh  = wcat + 3 * NW;
    u16* vpT  = woh + NW;            // (16*8*64, 512)
    u16* cxh  = vpT + NE;            // (8192, 512)
    float* bcat = (float*)(cxh + NE);
    float* mDb  = bcat + 1536;

    cvt4_bf16<<<dim3((unsigned)(NW/8/256), 4), 256, 0, stream>>>(
        Wq, Wk, Wv, Wo, wcat, wcat + NW, wcat + 2*NW, woh, (int)NW);
    bcat_k<<<6, 256, 0, stream>>>(bq, bk, bv, bcat);

    gemm_qkv<<<dim3(64, 4, 3), 256, 0, stream>>>(query, key, value, wcat, bcat, pkv);

    conv_gate_all<<<(int)(NTOK / 4), 256, 0, stream>>>(
        key, pkv, Wcq, Wck, Wcv, Wgq, bgq, Wgk, bgk, Wgv, bgv, WmD, bmD, mDb);

    vtrans<<<dim3(8, 8, 16), 256, 0, stream>>>(pkv, vpT);

    attn_mfma<<<dim3(128, 8), 256, 0, stream>>>(pkv, vpT, mDb, mask, rpe, cxh);

    gemm_out<<<dim3(64, 4), 256, 0, stream>>>(cxh, woh, bo, out, (int)NTOK, NSZ, NSZ);
}

// Round 10
// 137.893 us; speedup vs baseline: 1.4392x; 1.1204x over previous
//
#include <hip/hip_runtime.h>
#include <math.h>

#define NB 16
#define NT 512
#define NSZ 512
#define NH 8
#define NHD 64
#define MAXR 16

#define C_D0 6.3f
#define C_STD 1.4f
#define C_GAMMA 2.0f

#define NEGINF (-1e30f)
#define LOG2E 1.4426950408889634f
#define C1F   0.18033688011112042f   // 0.125 * log2(e)

typedef unsigned short u16;
typedef __attribute__((ext_vector_type(8))) short bf16x8;
typedef __attribute__((ext_vector_type(4))) float f32x4;
typedef __attribute__((ext_vector_type(8))) unsigned short u16x8;

__device__ __forceinline__ u16 f2b(float f) {
    union { float f; unsigned int u; } c; c.f = f;
    unsigned int u = c.u + 0x7FFFu + ((c.u >> 16) & 1u);
    return (u16)(u >> 16);
}
__device__ __forceinline__ float b2f(u16 h) {
    union { unsigned int u; float f; } c; c.u = ((unsigned int)h) << 16;
    return c.f;
}

#if __has_builtin(__builtin_amdgcn_exp2f)
__device__ __forceinline__ float exp2_fast(float x) { return __builtin_amdgcn_exp2f(x); }
#else
__device__ __forceinline__ float exp2_fast(float x) { return exp2f(x); }
#endif

#define GL2LDS(gp, lp) __builtin_amdgcn_global_load_lds( \
    (const __attribute__((address_space(1))) void*)(gp), \
    (__attribute__((address_space(3))) void*)(lp), 16, 0, 0)

// swizzled u16-index of 16B chunk c in row r (row = 8 chunks = 64 bf16)
#define SWU(r, c) ((((r) * 8) + ((c) ^ ((r) & 7))) * 8)

// ---------------------------------------------------------------------------
// fp32 -> bf16 convert (weights only)
// ---------------------------------------------------------------------------
__global__ __launch_bounds__(256) void cvt4_bf16(
    const float* __restrict__ s0, const float* __restrict__ s1,
    const float* __restrict__ s2, const float* __restrict__ s3,
    u16* __restrict__ d0, u16* __restrict__ d1,
    u16* __restrict__ d2, u16* __restrict__ d3, int n)
{
    const float* s; u16* d;
    switch (blockIdx.y) {
        case 0: s = s0; d = d0; break;
        case 1: s = s1; d = d1; break;
        case 2: s = s2; d = d2; break;
        default: s = s3; d = d3; break;
    }
    int i = (blockIdx.x * 256 + threadIdx.x) * 8;
    if (i >= n) return;
    float4 a = *(const float4*)&s[i];
    float4 b = *(const float4*)&s[i + 4];
    u16x8 v;
    v[0]=f2b(a.x); v[1]=f2b(a.y); v[2]=f2b(a.z); v[3]=f2b(a.w);
    v[4]=f2b(b.x); v[5]=f2b(b.y); v[6]=f2b(b.z); v[7]=f2b(b.w);
    *(u16x8*)&d[i] = v;
}

// ---------------------------------------------------------------------------
// QKV projections, z-batched. A fp32 reg-staged with in-flight bf16 convert.
// ---------------------------------------------------------------------------
__global__ __launch_bounds__(256) void gemm_qkv(
    const float* __restrict__ A0, const float* __restrict__ A1, const float* __restrict__ A2,
    const u16* __restrict__ Wc,
    const float* __restrict__ bq, const float* __restrict__ bk, const float* __restrict__ bv,
    u16* __restrict__ pkv)
{
    __shared__ u16 Al[128 * 32];
    __shared__ u16 Bl[128 * 32];
    const int z = blockIdx.z;
    const float* A = z == 0 ? A0 : (z == 1 ? A1 : A2);
    const u16* W = Wc + (size_t)z * NSZ * NSZ;
    const float* bias = z == 0 ? bq : (z == 1 ? bk : bv);
    const int tid = threadIdx.x;
    const int m0 = blockIdx.x * 128;
    const int n0 = blockIdx.y * 128;
    const int w = tid >> 6, lane = tid & 63;
    const int wm = (w >> 1) * 64, wn = (w & 1) * 64;
    const int fr = lane & 15, fk = lane >> 4;

    f32x4 acc[4][4] = {};
    for (int k0 = 0; k0 < NSZ; k0 += 32) {
        float4 a0[2], a1[2];
        #pragma unroll
        for (int p = 0; p < 2; ++p) {
            int s = tid + p * 256;
            int row = s >> 2, cb = s & 3;
            const float* ga = &A[(size_t)(m0 + row) * NSZ + k0 + cb * 8];
            a0[p] = *(const float4*)ga;
            a1[p] = *(const float4*)(ga + 4);
            GL2LDS(&W[(size_t)(n0 + row) * NSZ + k0 + cb * 8], &Bl[s * 8]);
        }
        #pragma unroll
        for (int p = 0; p < 2; ++p) {
            int s = tid + p * 256;
            u16x8 v;
            v[0]=f2b(a0[p].x); v[1]=f2b(a0[p].y); v[2]=f2b(a0[p].z); v[3]=f2b(a0[p].w);
            v[4]=f2b(a1[p].x); v[5]=f2b(a1[p].y); v[6]=f2b(a1[p].z); v[7]=f2b(a1[p].w);
            *(u16x8*)&Al[s * 8] = v;
        }
        __syncthreads();
        bf16x8 af[4], bfr[4];
        #pragma unroll
        for (int mf = 0; mf < 4; ++mf)
            af[mf] = *(const bf16x8*)&Al[(wm + mf * 16 + fr) * 32 + fk * 8];
        #pragma unroll
        for (int nf = 0; nf < 4; ++nf)
            bfr[nf] = *(const bf16x8*)&Bl[(wn + nf * 16 + fr) * 32 + fk * 8];
        #pragma unroll
        for (int mf = 0; mf < 4; ++mf)
            #pragma unroll
            for (int nf = 0; nf < 4; ++nf)
                acc[mf][nf] = __builtin_amdgcn_mfma_f32_16x16x32_bf16(
                    af[mf], bfr[nf], acc[mf][nf], 0, 0, 0);
        __syncthreads();
    }
    #pragma unroll
    for (int mf = 0; mf < 4; ++mf) {
        #pragma unroll
        for (int nf = 0; nf < 4; ++nf) {
            int col = n0 + wn + nf * 16 + fr;
            float bvv = bias[col];
            #pragma unroll
            for (int r = 0; r < 4; ++r) {
                int rowg = m0 + wm + mf * 16 + fk * 4 + r;
                pkv[(size_t)rowg * 1536 + z * 512 + col] = f2b(acc[mf][nf][r] + bvv);
            }
        }
    }
}

// ---------------------------------------------------------------------------
// Output projection (fp32 out). 64x128 tile, 4 waves (2x2, 32x64 wave tile),
// 12 KB LDS -> 2 blocks/CU (was 1 at 128x128).
// ---------------------------------------------------------------------------
__global__ __launch_bounds__(256) void gemm_out(
    const u16* __restrict__ A, const u16* __restrict__ W,
    const float* __restrict__ bias, float* __restrict__ Cout, int M, int N, int K)
{
    __shared__ u16 Al[64 * 32];
    __shared__ u16 Bl[128 * 32];
    const int tid = threadIdx.x;
    const int m0 = blockIdx.x * 64;
    const int n0 = blockIdx.y * 128;
    const int w = tid >> 6, lane = tid & 63;
    const int wm = (w >> 1) * 32, wn = (w & 1) * 64;
    const int fr = lane & 15, fk = lane >> 4;

    f32x4 acc[2][4] = {};
    for (int k0 = 0; k0 < K; k0 += 32) {
        {
            int row = tid >> 2, cb = tid & 3;
            GL2LDS(&A[(size_t)(m0 + row) * K + k0 + cb * 8], &Al[tid * 8]);
        }
        #pragma unroll
        for (int p = 0; p < 2; ++p) {
            int s = tid + p * 256;
            int row = s >> 2, cb = s & 3;
            GL2LDS(&W[(size_t)(n0 + row) * K + k0 + cb * 8], &Bl[s * 8]);
        }
        __syncthreads();
        bf16x8 af[2], bfr[4];
        #pragma unroll
        for (int mf = 0; mf < 2; ++mf)
            af[mf] = *(const bf16x8*)&Al[(wm + mf * 16 + fr) * 32 + fk * 8];
        #pragma unroll
        for (int nf = 0; nf < 4; ++nf)
            bfr[nf] = *(const bf16x8*)&Bl[(wn + nf * 16 + fr) * 32 + fk * 8];
        #pragma unroll
        for (int mf = 0; mf < 2; ++mf)
            #pragma unroll
            for (int nf = 0; nf < 4; ++nf)
                acc[mf][nf] = __builtin_amdgcn_mfma_f32_16x16x32_bf16(
                    af[mf], bfr[nf], acc[mf][nf], 0, 0, 0);
        __syncthreads();
    }
    #pragma unroll
    for (int mf = 0; mf < 2; ++mf) {
        #pragma unroll
        for (int nf = 0; nf < 4; ++nf) {
            int col = n0 + wn + nf * 16 + fr;
            float bv = bias[col];
            #pragma unroll
            for (int r = 0; r < 4; ++r) {
                int rowg = m0 + wm + mf * 16 + fk * 4 + r;
                Cout[(size_t)rowg * N + col] = acc[mf][nf][r] + bv;
            }
        }
    }
}

// ---------------------------------------------------------------------------
// Fused 3x depthwise conv1d(k=5) + 3 scalar gates + mD. xn raw fp32 key.
// ---------------------------------------------------------------------------
__global__ __launch_bounds__(256) void conv_gate_all(
    const float* __restrict__ xn, u16* __restrict__ pkv,
    const float* __restrict__ Wcq, const float* __restrict__ Wck, const float* __restrict__ Wcv,
    const float* __restrict__ Wgq, const float* __restrict__ bgq,
    const float* __restrict__ Wgk, const float* __restrict__ bgk,
    const float* __restrict__ Wgv, const float* __restrict__ bgv,
    const float* __restrict__ WmD, const float* __restrict__ bmD,
    float* __restrict__ mD)
{
    const int w = threadIdx.x >> 6, lane = threadIdx.x & 63;
    const int bt = blockIdx.x * 4 + w;
    const int b = bt >> 9, tpos = bt & (NT - 1);
    const int c0 = lane * 8;

    float x[5][8];
    #pragma unroll
    for (int j = 0; j < 5; ++j) {
        int tt = tpos + j - 2;
        if (tt >= 0 && tt < NT) {
            const float4* xp = (const float4*)&xn[((size_t)(b*NT + tt))*NSZ + c0];
            float4 u0 = xp[0], u1 = xp[1];
            x[j][0]=u0.x; x[j][1]=u0.y; x[j][2]=u0.z; x[j][3]=u0.w;
            x[j][4]=u1.x; x[j][5]=u1.y; x[j][6]=u1.z; x[j][7]=u1.w;
        } else {
            #pragma unroll
            for (int i = 0; i < 8; ++i) x[j][i] = 0.f;
        }
    }
    const size_t rb = (size_t)bt * 1536;
    u16x8 q8 = *(const u16x8*)&pkv[rb + c0];
    u16x8 k8 = *(const u16x8*)&pkv[rb + 512 + c0];
    u16x8 v8 = *(const u16x8*)&pkv[rb + 1024 + c0];

    float aq[8], ak[8], av[8];
    float sq = 0.f, sk = 0.f, sv = 0.f;
    #pragma unroll
    for (int i = 0; i < 8; ++i) {
        int c = c0 + i;
        float a0 = 0.f, a1 = 0.f, a2 = 0.f;
        #pragma unroll
        for (int j = 0; j < 5; ++j) {
            a0 += x[j][i] * Wcq[c*5 + j];
            a1 += x[j][i] * Wck[c*5 + j];
            a2 += x[j][i] * Wcv[c*5 + j];
        }
        aq[i] = a0; ak[i] = a1; av[i] = a2;
        sq += b2f(q8[i]) * Wgq[c] + a0 * Wgq[512 + c];
        sk += b2f(k8[i]) * Wgk[c] + a1 * Wgk[512 + c];
        sv += b2f(v8[i]) * Wgv[c] + a2 * Wgv[512 + c];
    }
    #pragma unroll
    for (int o = 1; o < 64; o <<= 1) {
        sq += __shfl_xor(sq, o, 64);
        sk += __shfl_xor(sk, o, 64);
        sv += __shfl_xor(sv, o, 64);
    }
    float gq = 1.f / (1.f + expf(-(sq + bgq[0])));
    float gk = 1.f / (1.f + expf(-(sk + bgk[0])));
    float gv = 1.f / (1.f + expf(-(sv + bgv[0])));

    u16x8 oq8, ok8, ov8;
    float smd = 0.f;
    #pragma unroll
    for (int i = 0; i < 8; ++i) {
        float oq = (1.f - gq) * b2f(q8[i]) + gq * aq[i];
        oq8[i] = f2b(oq);
        ok8[i] = f2b((1.f - gk) * b2f(k8[i]) + gk * ak[i]);
        ov8[i] = f2b((1.f - gv) * b2f(v8[i]) + gv * av[i]);
        smd += oq * WmD[c0 + i];
    }
    *(u16x8*)&pkv[rb + c0]        = oq8;
    *(u16x8*)&pkv[rb + 512 + c0]  = ok8;
    *(u16x8*)&pkv[rb + 1024 + c0] = ov8;
    #pragma unroll
    for (int o = 1; o < 64; o <<= 1) smd += __shfl_xor(smd, o, 64);
    if (lane == 0)
        mD[bt] = C_D0 + 2.f * C_STD * tanhf((smd + bmD[0]) / C_GAMMA);
}

// ---------------------------------------------------------------------------
// V transpose: pkv v-section (b,t,h*64+d) -> vpT[(b*8+h)*64+d][t]
// ---------------------------------------------------------------------------
__global__ __launch_bounds__(256) void vtrans(
    const u16* __restrict__ pkv, u16* __restrict__ vpT)
{
    __shared__ u16 lt[64][72];
    const int t0 = blockIdx.x * 64;
    const int h = blockIdx.y, b = blockIdx.z;
    const int tid = threadIdx.x;
    #pragma unroll
    for (int p = 0; p < 2; ++p) {
        int s = tid + p * 256;
        int t = s >> 3, c8 = s & 7;
        u16x8 v = *(const u16x8*)&pkv[((size_t)(b*NT + t0 + t))*1536 + 1024 + h*NHD + c8*8];
        *(u16x8*)&lt[t][c8 * 8] = v;
    }
    __syncthreads();
    #pragma unroll
    for (int p = 0; p < 2; ++p) {
        int s = tid + p * 256;
        int d = s >> 3, c8 = s & 7;
        u16x8 o;
        #pragma unroll
        for (int j = 0; j < 8; ++j) o[j] = lt[c8 * 8 + j][d];
        *(u16x8*)&vpT[((size_t)((b*NH + h)*NHD + d))*NT + t0 + c8*8] = o;
    }
}

// ---------------------------------------------------------------------------
// MFMA flash attention — shifted 2-tile window.
// Every q in [q0,q0+64) needs only keys [q0-32, q0+96): dropped keys are
// suppressed >=26 nats by the Gaussian decay (e-26 ~ 5e-12 relative).
// Window base w0 = max(0, min(q0-32, L-128)) gives exactly 2 k-tiles and
// guarantees key L-1 in-window for q>=L rows; both tiles always contain an
// unmasked key. Per-tile mask = computed predicate (kg >= L), no loads.
// ---------------------------------------------------------------------------
__global__ __launch_bounds__(256) void attn_mfma(
    const u16* __restrict__ pkv, const u16* __restrict__ vpT,
    const float* __restrict__ mD, const int* __restrict__ mask,
    const float* __restrict__ rpe, u16* __restrict__ cxh)
{
    __shared__ __align__(16) char smem[38144];
    u16*  QP    = (u16*)(smem);              // Q (prologue), P (loop), wA (epi)
    u16*  Kl    = (u16*)(smem + 8192);       // K tile; epi: rvl linear / out-bounce
    u16*  Vl    = (u16*)(smem + 16384);      // V tile; prologue: rpk; epi: rvT
    u16*  rpk   = (u16*)(smem + 16384);
    u16*  rvl16 = (u16*)(smem + 8192);
    u16*  qdrl  = (u16*)(smem + 24576);      // [64][36] bf16
    float* wbufl= (float*)(smem + 29184);    // [64][34] fp32 (col 33 stays 0)
    float* inv2s= (float*)(smem + 37888);    // [64]

    const int tid  = threadIdx.x;
    const int lane = tid & 63;
    const int w    = tid >> 6;
    const int wq0  = w * 16;
    const int fr   = lane & 15;
    const int fq   = lane >> 4;
    const int b    = blockIdx.x >> 3;
    const int h    = blockIdx.x & 7;
    const int q0   = blockIdx.y * 64;

    const size_t qbase  = ((size_t)(b*NT + q0)) * 1536 + h * NHD;
    const size_t kbaseg = ((size_t)b * NT) * 1536 + 512 + h * NHD;
    const size_t vbaseg = ((size_t)((b*NH + h) * NHD)) * NT;

    // ---- sequence length L (first masked key), per-wave shuffle-min ----
    int Lm = 512;
    #pragma unroll
    for (int j = 0; j < 8; ++j) {
        if (mask[b * NT + lane + 64 * j]) Lm = min(Lm, lane + 64 * j);
    }
    #pragma unroll
    for (int o = 1; o < 64; o <<= 1) Lm = min(Lm, __shfl_xor(Lm, o, 64));
    const int L = Lm;
    const int w0 = max(0, min(q0 - 32, L - 128));

    // ---- prologue: reg-load Q, K[w0], V[w0]; swizzled ds_write of Q, K ----
    int r_[2], cs_[2];
    u16x8 qreg[2], kreg[2], vreg[2];
    #pragma unroll
    for (int p = 0; p < 2; ++p) {
        int s = tid + p * 256;
        r_[p] = s >> 3; cs_[p] = s & 7;
        qreg[p] = *(const u16x8*)(pkv + qbase  + (size_t)r_[p] * 1536 + cs_[p] * 8);
        kreg[p] = *(const u16x8*)(pkv + kbaseg + (size_t)(w0 + r_[p]) * 1536 + cs_[p] * 8);
        vreg[p] = *(const u16x8*)(vpT + vbaseg + (size_t)r_[p] * NT + w0 + cs_[p] * 8);
    }
    #pragma unroll
    for (int p = 0; p < 2; ++p) {
        *(u16x8*)(QP + SWU(r_[p], cs_[p])) = qreg[p];
        *(u16x8*)(Kl + SWU(r_[p], cs_[p])) = kreg[p];
    }
    // rpe_k -> rpk (in Vl space): 264 chunks, strided (264 > 256 threads!)
    for (int idx = tid; idx < 264; idx += 256) {
        int r = idx >> 3, c = idx & 7;
        float4 f0 = *(const float4*)&rpe[r * 128 + c * 8];
        float4 f1 = *(const float4*)&rpe[r * 128 + c * 8 + 4];
        u16x8 vv;
        vv[0]=f2b(f0.x); vv[1]=f2b(f0.y); vv[2]=f2b(f0.z); vv[3]=f2b(f0.w);
        vv[4]=f2b(f1.x); vv[5]=f2b(f1.y); vv[6]=f2b(f1.z); vv[7]=f2b(f1.w);
        *(u16x8*)(rpk + SWU(r, c)) = vv;
    }
    if (tid < 120) {   // zero rows 33..47
        u16x8 vv = {0,0,0,0,0,0,0,0};
        *(u16x8*)(rpk + (((33 + (tid >> 3)) * 8) + (tid & 7)) * 8) = vv;
    }
    if (tid < 64) {
        float md = mD[b * NT + q0 + tid];
        inv2s[tid] = 2.f * LOG2E / (md * md);
    }
    for (int i = tid; i < 64 * 34; i += 256) wbufl[i] = 0.f;
    __syncthreads();                                // (P0)

    // persistent Q A-frags (QP becomes Pl afterwards)
    bf16x8 aq0 = *(const bf16x8*)(QP + SWU(wq0 + fr, fq));
    bf16x8 aq1 = *(const bf16x8*)(QP + SWU(wq0 + fr, 4 + fq));

    // qdr[q][rd] = q . rpe_k[rd] via MFMA (reads rpk in Vl space)
    {
        f32x4 qd[3] = {};
        #pragma unroll
        for (int nf = 0; nf < 3; ++nf) {
            bf16x8 b0 = *(const bf16x8*)(rpk + SWU(nf * 16 + fr, fq));
            bf16x8 b1 = *(const bf16x8*)(rpk + SWU(nf * 16 + fr, 4 + fq));
            qd[nf] = __builtin_amdgcn_mfma_f32_16x16x32_bf16(aq0, b0, qd[nf], 0, 0, 0);
            qd[nf] = __builtin_amdgcn_mfma_f32_16x16x32_bf16(aq1, b1, qd[nf], 0, 0, 0);
        }
        #pragma unroll
        for (int nf = 0; nf < 3; ++nf) {
            int rd = nf * 16 + fr;
            if (rd < 33) {
                #pragma unroll
                for (int r = 0; r < 4; ++r)
                    qdrl[(wq0 + fq * 4 + r) * 36 + rd] = f2b(qd[nf][r]);
            }
        }
    }
    __syncthreads();                                // (P1) qdr done; rpk dead
    // V[w0] ds_write into Vl (visible at first iter's barrier (1))
    #pragma unroll
    for (int p = 0; p < 2; ++p)
        *(u16x8*)(Vl + SWU(r_[p], cs_[p])) = vreg[p];

    f32x4 O[4] = {};
    float m2[4] = {NEGINF, NEGINF, NEGINF, NEGINF};
    float li[4] = {};

    #pragma unroll
    for (int t = 0; t < 2; ++t) {
        const int kb = w0 + t * 64;
        const bool pre = (t == 0);
        u16x8 kreg2[2], vreg2[2];
        if (pre) {
            const int kn = kb + 64;
            #pragma unroll
            for (int p = 0; p < 2; ++p) {
                kreg2[p] = *(const u16x8*)(pkv + kbaseg + (size_t)(kn + r_[p]) * 1536 + cs_[p] * 8);
                vreg2[p] = *(const u16x8*)(vpT + vbaseg + (size_t)r_[p] * NT + kn + cs_[p] * 8);
            }
        }
        int mk[4];
        #pragma unroll
        for (int nf = 0; nf < 4; ++nf) mk[nf] = (kb + nf * 16 + fr) >= L;

        // ---- QK^T ----
        f32x4 s_[4] = {};
        #pragma unroll
        for (int nf = 0; nf < 4; ++nf) {
            bf16x8 b0 = *(const bf16x8*)(Kl + SWU(nf * 16 + fr, fq));
            bf16x8 b1 = *(const bf16x8*)(Kl + SWU(nf * 16 + fr, 4 + fq));
            s_[nf] = __builtin_amdgcn_mfma_f32_16x16x32_bf16(aq0, b0, s_[nf], 0, 0, 0);
            s_[nf] = __builtin_amdgcn_mfma_f32_16x16x32_bf16(aq1, b1, s_[nf], 0, 0, 0);
        }
        // ---- softmax (log2 domain) ----
        const bool leftfar  = (kb + 79 <= q0);
        const bool rightfar = (kb >= q0 + 79);
        const bool mid = !leftfar && !rightfar;

        float p_[4][4], alpha[4], rsum_[4], ls_[4], rs_[4];
        #pragma unroll
        for (int r = 0; r < 4; ++r) {
            const int lq = wq0 + fq * 4 + r;
            const int qg = q0 + lq;
            const float iv = inv2s[lq];
            const float qf = leftfar ? b2f(qdrl[lq * 36]) : (rightfar ? b2f(qdrl[lq * 36 + 32]) : 0.f);
            float mx = NEGINF;
            #pragma unroll
            for (int nf = 0; nf < 4; ++nf) {
                const int kg = kb + nf * 16 + fr;
                float sc;
                if (mk[nf]) sc = NEGINF;
                else {
                    float qr = mid ? b2f(qdrl[lq * 36 + (min(max(kg - qg, -MAXR), MAXR) + MAXR)]) : qf;
                    float fd = (float)(qg - kg);
                    sc = (s_[nf][r] + qr) * C1F - fd * fd * iv;
                }
                p_[r][nf] = sc;
                mx = fmaxf(mx, sc);
            }
            mx = fmaxf(mx, __shfl_xor(mx, 1, 64));
            mx = fmaxf(mx, __shfl_xor(mx, 2, 64));
            mx = fmaxf(mx, __shfl_xor(mx, 4, 64));
            mx = fmaxf(mx, __shfl_xor(mx, 8, 64));
            float mn = fmaxf(m2[r], mx);
            alpha[r] = exp2_fast(m2[r] - mn);
            m2[r] = mn;
            float rsum = 0.f, ls = 0.f, rs = 0.f;
            #pragma unroll
            for (int nf = 0; nf < 4; ++nf) {
                float pv = exp2_fast(p_[r][nf] - mn);
                p_[r][nf] = pv;
                rsum += pv;
                if (mid) {
                    int kg = kb + nf * 16 + fr;
                    if (kg <= qg - MAXR) ls += pv;
                    else if (kg >= qg + MAXR) rs += pv;
                }
            }
            rsum += __shfl_xor(rsum, 1, 64); rsum += __shfl_xor(rsum, 2, 64);
            rsum += __shfl_xor(rsum, 4, 64); rsum += __shfl_xor(rsum, 8, 64);
            if (mid) {
                ls += __shfl_xor(ls, 1, 64); ls += __shfl_xor(ls, 2, 64);
                ls += __shfl_xor(ls, 4, 64); ls += __shfl_xor(ls, 8, 64);
                rs += __shfl_xor(rs, 1, 64); rs += __shfl_xor(rs, 2, 64);
                rs += __shfl_xor(rs, 4, 64); rs += __shfl_xor(rs, 8, 64);
            }
            li[r] = li[r] * alpha[r] + rsum;
            rsum_[r] = rsum; ls_[r] = ls; rs_[r] = rs;
        }
        // O rescale
        #pragma unroll
        for (int nf = 0; nf < 4; ++nf) {
            O[nf][0] *= alpha[0]; O[nf][1] *= alpha[1];
            O[nf][2] *= alpha[2]; O[nf][3] *= alpha[3];
        }
        // wbuf rescale + tile contributions
        #pragma unroll
        for (int r = 0; r < 4; ++r) {
            int lq = wq0 + fq * 4 + r;
            if (alpha[r] != 1.f) {
                for (int c = fr; c < 33; c += 16) wbufl[lq * 34 + c] *= alpha[r];
            }
        }
        if (fr == 0) {
            #pragma unroll
            for (int r = 0; r < 4; ++r) {
                int lq = wq0 + fq * 4 + r;
                if (leftfar)       wbufl[lq * 34]      += rsum_[r];
                else if (rightfar) wbufl[lq * 34 + 32] += rsum_[r];
                else { wbufl[lq * 34] += ls_[r]; wbufl[lq * 34 + 32] += rs_[r]; }
            }
        }
        if (mid) {
            #pragma unroll
            for (int r = 0; r < 4; ++r) {
                int lq = wq0 + fq * 4 + r, qg = q0 + lq;
                #pragma unroll
                for (int nf = 0; nf < 4; ++nf) {
                    int d = kb + nf * 16 + fr - qg;
                    if (d > -MAXR && d < MAXR) wbufl[lq * 34 + d + MAXR] += p_[r][nf];
                }
            }
        }
        // ---- P -> bf16 LDS (swizzled, in QP space) ----
        #pragma unroll
        for (int r = 0; r < 4; ++r) {
            int lq = wq0 + fq * 4 + r;
            #pragma unroll
            for (int nf = 0; nf < 4; ++nf) {
                int k = nf * 16 + fr;
                QP[lq * 64 + (((k >> 3) ^ (lq & 7)) << 3) + (k & 7)] = f2b(p_[r][nf]);
            }
        }
        __syncthreads();    // (1) P + V(t) visible; all QK reads of Kl done
        // K(t+1) into Kl (QK done; PV doesn't touch Kl)
        if (pre) {
            #pragma unroll
            for (int p = 0; p < 2; ++p)
                *(u16x8*)(Kl + SWU(r_[p], cs_[p])) = kreg2[p];
        }
        // ---- PV ----
        bf16x8 ap0 = *(const bf16x8*)(QP + SWU(wq0 + fr, fq));
        bf16x8 ap1 = *(const bf16x8*)(QP + SWU(wq0 + fr, 4 + fq));
        #pragma unroll
        for (int nf = 0; nf < 4; ++nf) {
            bf16x8 v0 = *(const bf16x8*)(Vl + SWU(nf * 16 + fr, fq));
            bf16x8 v1 = *(const bf16x8*)(Vl + SWU(nf * 16 + fr, 4 + fq));
            O[nf] = __builtin_amdgcn_mfma_f32_16x16x32_bf16(ap0, v0, O[nf], 0, 0, 0);
            O[nf] = __builtin_amdgcn_mfma_f32_16x16x32_bf16(ap1, v1, O[nf], 0, 0, 0);
        }
        __syncthreads();    // (2) PV reads of Vl/QP done; K(t+1) visible
        // V(t+1) into Vl (visible at next iter's barrier (1))
        if (pre) {
            #pragma unroll
            for (int p = 0; p < 2; ++p)
                *(u16x8*)(Vl + SWU(r_[p], cs_[p])) = vreg2[p];
        }
    }

    // ---- epilogue: O += wbuf @ rpe_v via MFMA ----
    for (int idx = tid; idx < 264; idx += 256) {   // strided: 264 > 256
        int r = idx >> 3, c = idx & 7;
        float4 f0 = *(const float4*)&rpe[r * 128 + 64 + c * 8];
        float4 f1 = *(const float4*)&rpe[r * 128 + 64 + c * 8 + 4];
        u16x8 vv;
        vv[0]=f2b(f0.x); vv[1]=f2b(f0.y); vv[2]=f2b(f0.z); vv[3]=f2b(f0.w);
        vv[4]=f2b(f1.x); vv[5]=f2b(f1.y); vv[6]=f2b(f1.z); vv[7]=f2b(f1.w);
        *(u16x8*)(rvl16 + (r * 8 + c) * 8) = vv;
    }
    // wA[q][rd] bf16 swizzled into QP; cols 34..63 zero (col 33 already 0)
    #pragma unroll
    for (int p = 0; p < 2; ++p) {
        int r = r_[p], cs = cs_[p];
        u16x8 vv;
        #pragma unroll
        for (int j = 0; j < 8; ++j) {
            int col = cs * 8 + j;
            vv[j] = (col < 34) ? f2b(wbufl[r * 34 + col]) : (u16)0;
        }
        *(u16x8*)(QP + SWU(r, cs)) = vv;
    }
    __syncthreads();   // (E1) rvl + wA ready (wbuf reads complete)
    // Build rvT[d][rd] bf16 swizzled into Vl from linear rvl16
    #pragma unroll
    for (int p = 0; p < 2; ++p) {
        int d = r_[p], cs = cs_[p];
        u16x8 vv;
        #pragma unroll
        for (int j = 0; j < 8; ++j) {
            int rd = cs * 8 + j;
            vv[j] = (rd < 33) ? rvl16[rd * 64 + d] : (u16)0;
        }
        *(u16x8*)(Vl + SWU(d, cs)) = vv;
    }
    __syncthreads();   // (E2) rvT ready
    {
        bf16x8 aw0 = *(const bf16x8*)(QP + SWU(wq0 + fr, fq));
        bf16x8 aw1 = *(const bf16x8*)(QP + SWU(wq0 + fr, 4 + fq));
        #pragma unroll
        for (int nf = 0; nf < 4; ++nf) {
            bf16x8 b0 = *(const bf16x8*)(Vl + SWU(nf * 16 + fr, fq));
            bf16x8 b1 = *(const bf16x8*)(Vl + SWU(nf * 16 + fr, 4 + fq));
            O[nf] = __builtin_amdgcn_mfma_f32_16x16x32_bf16(aw0, b0, O[nf], 0, 0, 0);
            O[nf] = __builtin_amdgcn_mfma_f32_16x16x32_bf16(aw1, b1, O[nf], 0, 0, 0);
        }
    }
    float invl[4];
    #pragma unroll
    for (int r = 0; r < 4; ++r) invl[r] = 1.f / li[r];
    #pragma unroll
    for (int r = 0; r < 4; ++r) {
        int lq = wq0 + fq * 4 + r;
        #pragma unroll
        for (int nf = 0; nf < 4; ++nf)
            Kl[lq * 64 + nf * 16 + fr] = f2b(O[nf][r] * invl[r]);   // linear bounce
    }
    __syncthreads();   // (E3)
    #pragma unroll
    for (int j = 0; j < 2; ++j) {
        int s = w * 128 + j * 64 + lane;
        int rr = s >> 3, c8 = s & 7;
        u16x8 vv = *(const u16x8*)(Kl + rr * 64 + c8 * 8);
        *(u16x8*)&cxh[((size_t)(b*NT + q0 + rr)) * 512 + h * NHD + c8 * 8] = vv;
    }
}

// ---------------------------------------------------------------------------
extern "C" void kernel_launch(void* const* d_in, const int* in_sizes, int n_in,
                              void* d_out, int out_size, void* d_ws, size_t ws_size,
                              hipStream_t stream) {
    const float* key   = (const float*)d_in[0];
    const float* value = (const float*)d_in[1];
    const float* query = (const float*)d_in[2];
    const int*   mask  = (const int*)d_in[3];
    const float* Wq  = (const float*)d_in[4];
    const float* bq  = (const float*)d_in[5];
    const float* Wk  = (const float*)d_in[6];
    const float* bk  = (const float*)d_in[7];
    const float* Wv  = (const float*)d_in[8];
    const float* bv  = (const float*)d_in[9];
    const float* Wcq = (const float*)d_in[10];
    const float* Wck = (const float*)d_in[11];
    const float* Wcv = (const float*)d_in[12];
    const float* Wgq = (const float*)d_in[13];
    const float* bgq = (const float*)d_in[14];
    const float* Wgk = (const float*)d_in[15];
    const float* bgk = (const float*)d_in[16];
    const float* Wgv = (const float*)d_in[17];
    const float* bgv = (const float*)d_in[18];
    const float* WmD = (const float*)d_in[19];
    const float* bmD = (const float*)d_in[20];
    const float* rpe = (const float*)d_in[21];
    const float* Wo  = (const float*)d_in[22];
    const float* bo  = (const float*)d_in[23];
    float* out = (float*)d_out;

    const size_t NTOK = (size_t)NB * NT;            // 8192
    const size_t NE   = NTOK * NSZ;                 // 4,194,304
    const size_t NW   = (size_t)NSZ * NSZ;          // 262,144

    u16* ws16 = (u16*)d_ws;
    u16* pkv  = ws16;                // (8192, 1536) q|k|v
    u16* wcat = pkv + NTOK * 1536;   // 3 x (512,512)
    u16* woh  = wcat + 3 * NW;
    u16* vpT  = woh + NW;            // (16*8*64, 512)
    u16* cxh  = vpT + NE;            // (8192, 512)
    float* mDb = (float*)(cxh + NE);

    cvt4_bf16<<<dim3((unsigned)(NW/8/256), 4), 256, 0, stream>>>(
        Wq, Wk, Wv, Wo, wcat, wcat + NW, wcat + 2*NW, woh, (int)NW);

    gemm_qkv<<<dim3(64, 4, 3), 256, 0, stream>>>(
        query, key, value, wcat, bq, bk, bv, pkv);

    conv_gate_all<<<(int)(NTOK / 4), 256, 0, stream>>>(
        key, pkv, Wcq, Wck, Wcv, Wgq, bgq, Wgk, bgk, Wgv, bgv, WmD, bmD, mDb);

    vtrans<<<dim3(8, 8, 16), 256, 0, stream>>>(pkv, vpT);

    attn_mfma<<<dim3(128, 8), 256, 0, stream>>>(pkv, vpT, mDb, mask, rpe, cxh);

    gemm_out<<<dim3(128, 4), 256, 0, stream>>>(cxh, woh, bo, out, (int)NTOK, NSZ, NSZ);
}